// Round 1
// baseline (2308.163 us; speedup 1.0000x reference)
//
#include <hip/hip_runtime.h>
#include <math.h>

static constexpr int D   = 128;
static constexpr int H   = 8;
static constexpr int DFF = 512;
static constexpr int LAYERS = 3;
static constexpr float CLAMP_V = 5.0f;
static constexpr float LN_EPS = 1e-5f;

__device__ inline float4 ld4(const float* p){ return *reinterpret_cast<const float4*>(p); }

// ---------------- CSR build ----------------
__global__ __launch_bounds__(256) void count_kernel(const int* __restrict__ dst,
                                                    int* __restrict__ deg, int E)
{
  int e = blockIdx.x*256 + threadIdx.x;
  if (e < E) atomicAdd(&deg[dst[e]], 1);
}

__global__ __launch_bounds__(1024) void scan_kernel(const int* __restrict__ deg,
    int* __restrict__ offs, int* __restrict__ cursor, int N)
{
  __shared__ int lds[1024];
  const int tid = threadIdx.x;
  const int C = (N + 1023) >> 10;
  const int lo = tid * C;
  const int hi = (lo + C < N) ? (lo + C) : N;
  int ss = 0;
  for (int n = lo; n < hi; n++) ss += deg[n];
  lds[tid] = ss;
  __syncthreads();
  for (int off = 1; off < 1024; off <<= 1) {
    int vv = (tid >= off) ? lds[tid - off] : 0;
    __syncthreads();
    lds[tid] += vv;
    __syncthreads();
  }
  int run = (tid == 0) ? 0 : lds[tid - 1];
  for (int n = lo; n < hi; n++) { offs[n] = run; cursor[n] = run; run += deg[n]; }
  if (tid == 1023) offs[N] = lds[1023];
}

__global__ __launch_bounds__(256) void fill_kernel(const int* __restrict__ dst,
    int* __restrict__ cursor, int* __restrict__ csr, int E)
{
  int e = blockIdx.x*256 + threadIdx.x;
  if (e < E) {
    int p = atomicAdd(&cursor[dst[e]], 1);
    csr[p] = e;
  }
}

// ---------------- encoder ----------------
__global__ __launch_bounds__(256) void encoder_kernel(
    const float* __restrict__ nf, const float* __restrict__ W,
    const float* __restrict__ b, float* __restrict__ h, int N)
{
  int n = blockIdx.x*2 + (threadIdx.x >> 7);
  int d = threadIdx.x & 127;
  if (n >= N) return;
  const float* nr = nf + (size_t)n*16;
  const float* wr = W  + (size_t)d*16;
  float s = b[d];
  #pragma unroll
  for (int kk = 0; kk < 16; kk++) s = fmaf(nr[kk], wr[kk], s);
  h[(size_t)n*D + d] = s;
}

// ---------------- GEMM: C[m][f] = act(sum_k A[m][k]*W[f][k] + bias[f]) ----------------
// nmat==3: blockIdx.y selects (W0,C0)/(W1,C1)/(W2,C2), f0=0 (fused QKV).
// nmat==1: W=W0, C=C0, f0=blockIdx.y*128.
template<int K, bool RELU>
__global__ __launch_bounds__(256) void gemm_tn(
    const float* __restrict__ A,
    const float* __restrict__ W0, const float* __restrict__ W1, const float* __restrict__ W2,
    const float* __restrict__ bias,
    float* __restrict__ C0, float* __restrict__ C1, float* __restrict__ C2,
    int M, int F, int nmat)
{
  __shared__ float As[32][136];
  __shared__ float Ws[32][136];
  const float* W; float* C; int f0;
  if (nmat > 1) {
    int s = blockIdx.y;
    W = (s == 0) ? W0 : ((s == 1) ? W1 : W2);
    C = (s == 0) ? C0 : ((s == 1) ? C1 : C2);
    f0 = 0;
  } else { W = W0; C = C0; f0 = blockIdx.y * 128; }

  const int tid = threadIdx.x;
  const int tx = tid & 15, ty = tid >> 4;
  const int m0 = blockIdx.x * 128;

  float acc[8][8];
  #pragma unroll
  for (int i = 0; i < 8; i++)
    #pragma unroll
    for (int jj = 0; jj < 8; jj++) acc[i][jj] = 0.f;

  const int r  = (tid >> 3) << 2;   // 0..124
  const int kq = (tid & 7) << 2;    // 0..28

  for (int kk = 0; kk < K; kk += 32) {
    #pragma unroll
    for (int i = 0; i < 4; i++) {
      int gm = m0 + r + i;
      float4 a4 = (gm < M) ? ld4(&A[(size_t)gm*K + kk + kq]) : float4{0.f,0.f,0.f,0.f};
      As[kq+0][r+i] = a4.x; As[kq+1][r+i] = a4.y; As[kq+2][r+i] = a4.z; As[kq+3][r+i] = a4.w;
    }
    #pragma unroll
    for (int i = 0; i < 4; i++) {
      int gf = f0 + r + i;
      float4 w4 = ld4(&W[(size_t)gf*K + kk + kq]);
      Ws[kq+0][r+i] = w4.x; Ws[kq+1][r+i] = w4.y; Ws[kq+2][r+i] = w4.z; Ws[kq+3][r+i] = w4.w;
    }
    __syncthreads();
    #pragma unroll
    for (int k2 = 0; k2 < 32; k2++) {
      float a[8], b[8];
      *(float4*)&a[0] = *(const float4*)&As[k2][ty*8];
      *(float4*)&a[4] = *(const float4*)&As[k2][ty*8+4];
      *(float4*)&b[0] = *(const float4*)&Ws[k2][tx*8];
      *(float4*)&b[4] = *(const float4*)&Ws[k2][tx*8+4];
      #pragma unroll
      for (int i = 0; i < 8; i++)
        #pragma unroll
        for (int jj = 0; jj < 8; jj++)
          acc[i][jj] = fmaf(a[i], b[jj], acc[i][jj]);
    }
    __syncthreads();
  }
  #pragma unroll
  for (int i = 0; i < 8; i++) {
    int gm = m0 + ty*8 + i;
    if (gm >= M) continue;
    #pragma unroll
    for (int jj = 0; jj < 8; jj++) {
      int gf = f0 + tx*8 + jj;
      float vv = acc[i][jj] + (bias ? bias[gf] : 0.f);
      if (RELU) vv = fmaxf(vv, 0.f);
      C[(size_t)gm*F + gf] = vv;
    }
  }
}

// ---------------- attention (CSR, per-node 16-lane group) ----------------
__global__ __launch_bounds__(256) void attn_kernel(
    const float* __restrict__ q, const float* __restrict__ k,
    const float* __restrict__ v, const int* __restrict__ src,
    const int* __restrict__ offs, const int* __restrict__ csr,
    float* __restrict__ ubuf, float* __restrict__ out, int N)
{
  __shared__ float qs[16][132];
  const int tid  = threadIdx.x;
  const int lane = tid & 63;
  const int wv   = tid >> 6;
  const int grp  = lane >> 4;
  const int j    = lane & 15;
  const int ln   = wv*4 + grp;
  const int n    = blockIdx.x*16 + ln;

  if (n < N) {
    float4 a = ld4(&q[(size_t)n*D + j*8]);
    float4 b = ld4(&q[(size_t)n*D + j*8 + 4]);
    *(float4*)&qs[ln][j*8]   = a;
    *(float4*)&qs[ln][j*8+4] = b;
  }
  __syncthreads();
  if (n >= N) return;

  const int start = offs[n];
  const int deg   = offs[n+1] - start;

  float m[H];
  #pragma unroll
  for (int hh = 0; hh < H; hh++) m[hh] = -1e30f;

  // phase 1: u = clamp(scale * q.k), track max
  for (int base = 0; base < deg; base += 16) {
    const int pos = base + j;
    if (pos < deg) {
      const int idx = start + pos;
      const int e   = csr[idx];
      const float* kr = k + (size_t)src[e]*D;
      float u[H];
      #pragma unroll
      for (int hh = 0; hh < H; hh++) {
        float dd = 0.f;
        #pragma unroll
        for (int t = 0; t < 16; t += 4) {
          float4 kv = ld4(&kr[hh*16 + t]);
          const float4 qv = *(const float4*)&qs[ln][hh*16 + t];
          dd += kv.x*qv.x + kv.y*qv.y + kv.z*qv.z + kv.w*qv.w;
        }
        float uu = dd * 0.25f;               // 1/sqrt(16)
        uu = fminf(fmaxf(uu, -CLAMP_V), CLAMP_V);
        u[hh] = uu;
        m[hh] = fmaxf(m[hh], uu);
      }
      *(float4*)&ubuf[(size_t)idx*8]     = make_float4(u[0],u[1],u[2],u[3]);
      *(float4*)&ubuf[(size_t)idx*8 + 4] = make_float4(u[4],u[5],u[6],u[7]);
    }
  }
  #pragma unroll
  for (int off = 1; off < 16; off <<= 1)
    #pragma unroll
    for (int hh = 0; hh < H; hh++) m[hh] = fmaxf(m[hh], __shfl_xor(m[hh], off));

  // phase 2+3: e = exp(u-m), s += e ; acc += e * v  (normalize at end)
  float s[H], acc[H];
  #pragma unroll
  for (int hh = 0; hh < H; hh++) { s[hh] = 0.f; acc[hh] = 0.f; }

  for (int base = 0; base < deg; base += 16) {
    const int pos = base + j;
    float e8[H];
    #pragma unroll
    for (int hh = 0; hh < H; hh++) e8[hh] = 0.f;
    if (pos < deg) {
      const int idx = start + pos;
      float4 u0 = ld4(&ubuf[(size_t)idx*8]);
      float4 u1 = ld4(&ubuf[(size_t)idx*8 + 4]);
      float uu[H] = {u0.x,u0.y,u0.z,u0.w,u1.x,u1.y,u1.z,u1.w};
      #pragma unroll
      for (int hh = 0; hh < H; hh++) { e8[hh] = __expf(uu[hh] - m[hh]); s[hh] += e8[hh]; }
    }
    const int cnt = (deg - base < 16) ? (deg - base) : 16;
    for (int t = 0; t < cnt; t++) {
      const int eid = csr[start + base + t];
      const int sn  = src[eid];
      const float* vr = v + (size_t)sn*D;
      #pragma unroll
      for (int hh = 0; hh < H; hh++) {
        float eh = __shfl(e8[hh], grp*16 + t);
        acc[hh] = fmaf(eh, vr[hh*16 + j], acc[hh]);
      }
    }
  }
  #pragma unroll
  for (int off = 1; off < 16; off <<= 1)
    #pragma unroll
    for (int hh = 0; hh < H; hh++) s[hh] += __shfl_xor(s[hh], off);

  #pragma unroll
  for (int hh = 0; hh < H; hh++) {
    float rs = (deg > 0) ? (1.0f / s[hh]) : 0.f;
    out[(size_t)n*D + hh*16 + j] = acc[hh] * rs;
  }
}

// ---------------- residual + layernorm: out = LN(A+B)*g + b ----------------
__global__ __launch_bounds__(256) void add_ln_kernel(
    const float* __restrict__ A, const float* __restrict__ B,
    const float* __restrict__ g, const float* __restrict__ bb,
    float* __restrict__ out, int N)
{
  int w = threadIdx.x >> 6, lane = threadIdx.x & 63;
  int n = blockIdx.x*4 + w;
  if (n >= N) return;
  size_t base = (size_t)n*D + lane*2;
  float x0 = A[base]   + B[base];
  float x1 = A[base+1] + B[base+1];
  float s = x0 + x1;
  #pragma unroll
  for (int off = 1; off < 64; off <<= 1) s += __shfl_xor(s, off);
  float mu = s * (1.0f/128.0f);
  float d0 = x0 - mu, d1 = x1 - mu;
  float ss = d0*d0 + d1*d1;
  #pragma unroll
  for (int off = 1; off < 64; off <<= 1) ss += __shfl_xor(ss, off);
  float r = rsqrtf(ss * (1.0f/128.0f) + LN_EPS);
  out[base]   = d0*r*g[lane*2]   + bb[lane*2];
  out[base+1] = d1*r*g[lane*2+1] + bb[lane*2+1];
}

// ---------------- decoder + mean ----------------
__global__ __launch_bounds__(256) void dec_partial(const float* __restrict__ h,
    const float* __restrict__ W, float* __restrict__ partials, int N)
{
  float acc = 0.f;
  for (int n = blockIdx.x*256 + threadIdx.x; n < N; n += 256*256) {
    const float* hr = h + (size_t)n*D;
    float s = 0.f;
    #pragma unroll
    for (int t = 0; t < 32; t++) {
      float4 hv = ld4(&hr[t*4]); float4 wv = ld4(&W[t*4]);
      s += hv.x*wv.x + hv.y*wv.y + hv.z*wv.z + hv.w*wv.w;
    }
    acc += s;
  }
  #pragma unroll
  for (int off = 1; off < 64; off <<= 1) acc += __shfl_xor(acc, off);
  __shared__ float red[4];
  int lane = threadIdx.x & 63, w = threadIdx.x >> 6;
  if (lane == 0) red[w] = acc;
  __syncthreads();
  if (threadIdx.x == 0) partials[blockIdx.x] = red[0]+red[1]+red[2]+red[3];
}

__global__ __launch_bounds__(256) void dec_final(const float* __restrict__ partials,
    const float* __restrict__ decb, float* __restrict__ out, int N)
{
  float a = partials[threadIdx.x];
  #pragma unroll
  for (int off = 1; off < 64; off <<= 1) a += __shfl_xor(a, off);
  __shared__ float red[4];
  int lane = threadIdx.x & 63, w = threadIdx.x >> 6;
  if (lane == 0) red[w] = a;
  __syncthreads();
  if (threadIdx.x == 0) out[0] = (red[0]+red[1]+red[2]+red[3]) / (float)N + decb[0];
}

// ---------------- launch ----------------
extern "C" void kernel_launch(void* const* d_in, const int* in_sizes, int n_in,
                              void* d_out, int out_size, void* d_ws, size_t ws_size,
                              hipStream_t stream)
{
  const float* nf   = (const float*)d_in[0];
  const int*   src  = (const int*)  d_in[1];
  const int*   dst  = (const int*)  d_in[2];
  const float* encW = (const float*)d_in[3];
  const float* encb = (const float*)d_in[4];
  const float* Wq   = (const float*)d_in[5];
  const float* Wk   = (const float*)d_in[6];
  const float* Wv   = (const float*)d_in[7];
  const float* Wo   = (const float*)d_in[8];
  const float* ln1g = (const float*)d_in[9];
  const float* ln1b = (const float*)d_in[10];
  const float* W1   = (const float*)d_in[11];
  const float* b1   = (const float*)d_in[12];
  const float* W2   = (const float*)d_in[13];
  const float* b2   = (const float*)d_in[14];
  const float* ln2g = (const float*)d_in[15];
  const float* ln2b = (const float*)d_in[16];
  const float* decW = (const float*)d_in[17];
  const float* decb = (const float*)d_in[18];
  float* out = (float*)d_out;

  const int N = in_sizes[0] / 16;
  const int E = in_sizes[1];

  float* ws   = (float*)d_ws;
  float* h    = ws;
  float* h1   = h    + (size_t)N*D;
  float* q    = h1   + (size_t)N*D;
  float* kbuf = q    + (size_t)N*D;
  float* vbuf = kbuf + (size_t)N*D;
  float* fb   = vbuf + (size_t)N*D;        // N*DFF floats, multi-use
  float* sum_av = fb;                       // [N,D]
  float* uh     = fb + (size_t)N*D;         // [N,D]
  float* ubuf   = fb + (size_t)2*N*D;       // [E,8]
  int* deg    = (int*)(fb + (size_t)N*DFF);
  int* offs   = deg + N;
  int* cursor = offs + N + 1;
  int* csr    = cursor + N;
  float* partials = (float*)(csr + E);

  // CSR build (dst -> incoming edge list)
  hipMemsetAsync(deg, 0, sizeof(int)*N, stream);
  count_kernel<<<(E+255)/256, 256, 0, stream>>>(dst, deg, E);
  scan_kernel<<<1, 1024, 0, stream>>>(deg, offs, cursor, N);
  fill_kernel<<<(E+255)/256, 256, 0, stream>>>(dst, cursor, csr, E);

  encoder_kernel<<<(N+1)/2, 256, 0, stream>>>(nf, encW, encb, h, N);

  const int gmx = (N + 127)/128;
  for (int l = 0; l < LAYERS; l++) {
    const float* wq = Wq + (size_t)l*D*D;
    const float* wk = Wk + (size_t)l*D*D;
    const float* wv = Wv + (size_t)l*D*D;
    const float* wo = Wo + (size_t)l*D*D;

    gemm_tn<128,false><<<dim3(gmx,3), 256, 0, stream>>>(
        h, wq, wk, wv, nullptr, q, kbuf, vbuf, N, D, 3);

    attn_kernel<<<(N+15)/16, 256, 0, stream>>>(q, kbuf, vbuf, src, offs, csr, ubuf, sum_av, N);

    gemm_tn<128,false><<<dim3(gmx,1), 256, 0, stream>>>(
        sum_av, wo, wo, wo, nullptr, uh, uh, uh, N, D, 1);

    add_ln_kernel<<<(N+3)/4, 256, 0, stream>>>(h, uh, ln1g + l*D, ln1b + l*D, h1, N);

    gemm_tn<128,true><<<dim3(gmx,4), 256, 0, stream>>>(
        h1, W1 + (size_t)l*DFF*D, nullptr, nullptr, b1 + l*DFF, fb, nullptr, nullptr, N, DFF, 1);

    gemm_tn<512,false><<<dim3(gmx,1), 256, 0, stream>>>(
        fb, W2 + (size_t)l*D*DFF, nullptr, nullptr, b2 + l*D, q, nullptr, nullptr, N, D, 1);

    add_ln_kernel<<<(N+3)/4, 256, 0, stream>>>(h1, q, ln2g + l*D, ln2b + l*D, h, N);
  }

  dec_partial<<<256, 256, 0, stream>>>(h, decW, partials, N);
  dec_final<<<1, 256, 0, stream>>>(partials, decb, out, N);
}

// Round 2
// 1110.205 us; speedup vs baseline: 2.0790x; 2.0790x over previous
//
#include <hip/hip_runtime.h>
#include <math.h>

static constexpr int D   = 128;
static constexpr int H   = 8;
static constexpr int DFF = 512;
static constexpr int LAYERS = 3;
static constexpr float CLAMP_V = 5.0f;
static constexpr float LN_EPS = 1e-5f;

typedef unsigned short u16;
typedef unsigned int   u32;
typedef short bf16x8 __attribute__((ext_vector_type(8)));
typedef float f32x4  __attribute__((ext_vector_type(4)));

__device__ inline float4 ld4(const float* p){ return *reinterpret_cast<const float4*>(p); }
__device__ inline u16 f2bf(float f){ u32 u = __float_as_uint(f); return (u16)((u + 0x7fff + ((u>>16)&1)) >> 16); }
__device__ inline float bf2f(u16 v){ return __uint_as_float(((u32)v) << 16); }
__device__ inline float bl(u32 u){ return __uint_as_float(u << 16); }
__device__ inline float bh(u32 u){ return __uint_as_float(u & 0xffff0000u); }

__device__ inline void gload_lds16(const void* g, void* l) {
  __builtin_amdgcn_global_load_lds(
      (const __attribute__((address_space(1))) void*)g,
      (__attribute__((address_space(3))) void*)l, 16, 0, 0);
}

// ---------------- CSR build ----------------
__global__ __launch_bounds__(256) void count_kernel(const int* __restrict__ dst,
                                                    int* __restrict__ deg, int E)
{
  int e = blockIdx.x*256 + threadIdx.x;
  if (e < E) atomicAdd(&deg[dst[e]], 1);
}

__global__ __launch_bounds__(1024) void scan_kernel(const int* __restrict__ deg,
    int* __restrict__ offs, int* __restrict__ cursor, int N)
{
  __shared__ int lds[1024];
  const int tid = threadIdx.x;
  const int C = (N + 1023) >> 10;
  const int lo = tid * C;
  const int hi = (lo + C < N) ? (lo + C) : N;
  int ss = 0;
  for (int n = lo; n < hi; n++) ss += deg[n];
  lds[tid] = ss;
  __syncthreads();
  for (int off = 1; off < 1024; off <<= 1) {
    int vv = (tid >= off) ? lds[tid - off] : 0;
    __syncthreads();
    lds[tid] += vv;
    __syncthreads();
  }
  int run = (tid == 0) ? 0 : lds[tid - 1];
  for (int n = lo; n < hi; n++) { offs[n] = run; cursor[n] = run; run += deg[n]; }
  if (tid == 1023) offs[N] = lds[1023];
}

__global__ __launch_bounds__(256) void fill_kernel(const int* __restrict__ dst,
    int* __restrict__ cursor, int* __restrict__ csr, int E)
{
  int e = blockIdx.x*256 + threadIdx.x;
  if (e < E) {
    int p = atomicAdd(&cursor[dst[e]], 1);
    csr[p] = e;
  }
}

// ---------------- weight conversion to bf16 ----------------
__global__ __launch_bounds__(256) void convert_weights(
    const float* __restrict__ Wq, const float* __restrict__ Wk, const float* __restrict__ Wv,
    const float* __restrict__ Wo, const float* __restrict__ W1, const float* __restrict__ W2,
    u16* __restrict__ out)
{
  const int SQKV = 3*384*128;
  const int SWO  = 3*128*128;
  const int SW1  = 3*512*128;
  const int SW2  = 3*128*512;
  int i = blockIdx.x*256 + threadIdx.x;
  if (i >= SQKV+SWO+SW1+SW2) return;
  float v;
  if (i < SQKV) {
    int l = i / (384*128), rem = i % (384*128);
    int row = rem / 128, col = rem % 128;
    const float* W = (row < 128) ? Wq : ((row < 256) ? Wk : Wv);
    v = W[(size_t)l*128*128 + (size_t)(row & 127)*128 + col];
  } else if (i < SQKV+SWO) {
    v = Wo[i - SQKV];
  } else if (i < SQKV+SWO+SW1) {
    v = W1[i - SQKV - SWO];
  } else {
    v = W2[i - SQKV - SWO - SW1];
  }
  out[i] = f2bf(v);
}

// ---------------- encoder (f32 + bf16 dual write) ----------------
__global__ __launch_bounds__(256) void encoder_kernel(
    const float* __restrict__ nf, const float* __restrict__ W,
    const float* __restrict__ b, float* __restrict__ h, u16* __restrict__ hb, int N)
{
  int n = blockIdx.x*2 + (threadIdx.x >> 7);
  int d = threadIdx.x & 127;
  if (n >= N) return;
  const float* nr = nf + (size_t)n*16;
  const float* wr = W  + (size_t)d*16;
  float s = b[d];
  #pragma unroll
  for (int kk = 0; kk < 16; kk++) s = fmaf(nr[kk], wr[kk], s);
  h[(size_t)n*D + d]  = s;
  hb[(size_t)n*D + d] = f2bf(s);
}

// ---------------- bf16 MFMA GEMM: C[m][f0+c] = act(sum_k A[m][k]*B[f0+c][k] + bias) ----
// A: [M][K] bf16.  B: [*][K] bf16 (row f0+r used by y-tile).  f0 = blockIdx.y*128.
template<int K, bool RELU, bool OUTBF>
__global__ __launch_bounds__(256) void gemm_mfma(
    const u16* __restrict__ A, const u16* __restrict__ B,
    const float* __restrict__ bias,
    float* __restrict__ Cf, u16* __restrict__ Cb,
    int M, int ldc)
{
  __shared__ u16 lA[128*64];
  __shared__ u16 lB[128*64];
  const int tid  = threadIdx.x;
  const int lane = tid & 63;
  const int wid  = tid >> 6;
  const int wr   = wid >> 1, wc = wid & 1;
  const int m0   = blockIdx.x * 128;
  const int f0   = blockIdx.y * 128;

  f32x4 acc[4][4];
  #pragma unroll
  for (int i = 0; i < 4; i++)
    #pragma unroll
    for (int j = 0; j < 4; j++) { acc[i][j][0]=0.f; acc[i][j][1]=0.f; acc[i][j][2]=0.f; acc[i][j][3]=0.f; }

  // staging: lane -> (row i>>3 of 8-row group, granule slot i&7); src granule pre-swizzled
  const int ldrow = lane >> 3;
  const int gran  = (lane & 7) ^ ldrow;

  #pragma unroll
  for (int ks = 0; ks < K/64; ks++) {
    __syncthreads();
    const int k0 = ks*64 + gran*8;
    #pragma unroll
    for (int is = 0; is < 4; is++) {
      const int r  = wid*32 + is*8;
      int gm = m0 + r + ldrow; if (gm >= M) gm = M - 1;
      gload_lds16(A + (size_t)gm*K + k0, &lA[r*64]);
      const int gf = f0 + r + ldrow;
      gload_lds16(B + (size_t)gf*K + k0, &lB[r*64]);
    }
    asm volatile("s_waitcnt vmcnt(0)" ::: "memory");
    __syncthreads();

    #pragma unroll
    for (int k2 = 0; k2 < 2; k2++) {
      bf16x8 af[4], bfr[4];
      const int kq = k2*4 + (lane >> 4);
      #pragma unroll
      for (int mi = 0; mi < 4; mi++) {
        const int r = wr*64 + mi*16 + (lane & 15);
        af[mi] = *(const bf16x8*)&lA[r*64 + ((kq ^ (r & 7)) << 3)];
      }
      #pragma unroll
      for (int ni = 0; ni < 4; ni++) {
        const int r = wc*64 + ni*16 + (lane & 15);
        bfr[ni] = *(const bf16x8*)&lB[r*64 + ((kq ^ (r & 7)) << 3)];
      }
      #pragma unroll
      for (int mi = 0; mi < 4; mi++)
        #pragma unroll
        for (int ni = 0; ni < 4; ni++)
          acc[mi][ni] = __builtin_amdgcn_mfma_f32_16x16x32_bf16(af[mi], bfr[ni], acc[mi][ni], 0, 0, 0);
    }
  }

  const int rbase = m0 + wr*64 + ((lane >> 4) << 2);
  const int cbase = f0 + wc*64 + (lane & 15);
  #pragma unroll
  for (int ni = 0; ni < 4; ni++) {
    const int col = cbase + ni*16;
    const float bv = bias ? bias[col] : 0.f;
    #pragma unroll
    for (int mi = 0; mi < 4; mi++) {
      #pragma unroll
      for (int r = 0; r < 4; r++) {
        const int gm = rbase + mi*16 + r;
        if (gm < M) {
          float v = acc[mi][ni][r] + bv;
          if (RELU) v = fmaxf(v, 0.f);
          if (OUTBF) Cb[(size_t)gm*ldc + col] = f2bf(v);
          else       Cf[(size_t)gm*ldc + col] = v;
        }
      }
    }
  }
}

// ---------------- attention (CSR, per-node 16-lane group; bf16 k/v) ----------------
__global__ __launch_bounds__(256) void attn_kernel(
    const float* __restrict__ q, const u16* __restrict__ kv,
    const int* __restrict__ src,
    const int* __restrict__ offs, const int* __restrict__ csr,
    float* __restrict__ ubuf, u16* __restrict__ outb, int N)
{
  __shared__ float qs[16][132];
  const int tid  = threadIdx.x;
  const int lane = tid & 63;
  const int wv   = tid >> 6;
  const int grp  = lane >> 4;
  const int j    = lane & 15;
  const int ln   = wv*4 + grp;
  const int n    = blockIdx.x*16 + ln;

  if (n < N) {
    float4 a = ld4(&q[(size_t)n*D + j*8]);
    float4 b = ld4(&q[(size_t)n*D + j*8 + 4]);
    *(float4*)&qs[ln][j*8]   = a;
    *(float4*)&qs[ln][j*8+4] = b;
  }
  __syncthreads();
  if (n >= N) return;

  const int start = offs[n];
  const int deg   = offs[n+1] - start;

  float m[H];
  #pragma unroll
  for (int hh = 0; hh < H; hh++) m[hh] = -1e30f;

  // phase 1: u = clamp(scale * q.k), track max
  for (int base = 0; base < deg; base += 16) {
    const int pos = base + j;
    if (pos < deg) {
      const int idx = start + pos;
      const int e   = csr[idx];
      const u16* kr = kv + (size_t)src[e]*256;
      float u[H];
      #pragma unroll
      for (int hh = 0; hh < H; hh++) {
        const float* qv = &qs[ln][hh*16];
        uint4 ka = *(const uint4*)(kr + hh*16);
        uint4 kb = *(const uint4*)(kr + hh*16 + 8);
        float dd = bl(ka.x)*qv[0] + bh(ka.x)*qv[1]
                 + bl(ka.y)*qv[2] + bh(ka.y)*qv[3]
                 + bl(ka.z)*qv[4] + bh(ka.z)*qv[5]
                 + bl(ka.w)*qv[6] + bh(ka.w)*qv[7]
                 + bl(kb.x)*qv[8] + bh(kb.x)*qv[9]
                 + bl(kb.y)*qv[10] + bh(kb.y)*qv[11]
                 + bl(kb.z)*qv[12] + bh(kb.z)*qv[13]
                 + bl(kb.w)*qv[14] + bh(kb.w)*qv[15];
        float uu = dd * 0.25f;
        uu = fminf(fmaxf(uu, -CLAMP_V), CLAMP_V);
        u[hh] = uu;
        m[hh] = fmaxf(m[hh], uu);
      }
      *(float4*)&ubuf[(size_t)idx*8]     = make_float4(u[0],u[1],u[2],u[3]);
      *(float4*)&ubuf[(size_t)idx*8 + 4] = make_float4(u[4],u[5],u[6],u[7]);
    }
  }
  #pragma unroll
  for (int off = 1; off < 16; off <<= 1)
    #pragma unroll
    for (int hh = 0; hh < H; hh++) m[hh] = fmaxf(m[hh], __shfl_xor(m[hh], off));

  float s[H], acc[H];
  #pragma unroll
  for (int hh = 0; hh < H; hh++) { s[hh] = 0.f; acc[hh] = 0.f; }

  for (int base = 0; base < deg; base += 16) {
    const int pos = base + j;
    float e8[H];
    #pragma unroll
    for (int hh = 0; hh < H; hh++) e8[hh] = 0.f;
    if (pos < deg) {
      const int idx = start + pos;
      float4 u0 = ld4(&ubuf[(size_t)idx*8]);
      float4 u1 = ld4(&ubuf[(size_t)idx*8 + 4]);
      float uu[H] = {u0.x,u0.y,u0.z,u0.w,u1.x,u1.y,u1.z,u1.w};
      #pragma unroll
      for (int hh = 0; hh < H; hh++) { e8[hh] = __expf(uu[hh] - m[hh]); s[hh] += e8[hh]; }
    }
    const int cnt = (deg - base < 16) ? (deg - base) : 16;
    for (int t = 0; t < cnt; t++) {
      const int eid = csr[start + base + t];
      const int sn  = src[eid];
      const u16* vr = kv + (size_t)sn*256 + 128;
      #pragma unroll
      for (int hh = 0; hh < H; hh++) {
        float eh = __shfl(e8[hh], grp*16 + t);
        acc[hh] = fmaf(eh, bf2f(vr[hh*16 + j]), acc[hh]);
      }
    }
  }
  #pragma unroll
  for (int off = 1; off < 16; off <<= 1)
    #pragma unroll
    for (int hh = 0; hh < H; hh++) s[hh] += __shfl_xor(s[hh], off);

  #pragma unroll
  for (int hh = 0; hh < H; hh++) {
    float rs = (deg > 0) ? (1.0f / s[hh]) : 0.f;
    outb[(size_t)n*D + hh*16 + j] = f2bf(acc[hh] * rs);
  }
}

// ---------------- residual + layernorm (dual write f32 + bf16) ----------------
__global__ __launch_bounds__(256) void add_ln_kernel(
    const float* __restrict__ A, const float* __restrict__ B,
    const float* __restrict__ g, const float* __restrict__ bb,
    float* __restrict__ out, u16* __restrict__ outb, int N)
{
  int w = threadIdx.x >> 6, lane = threadIdx.x & 63;
  int n = blockIdx.x*4 + w;
  if (n >= N) return;
  size_t base = (size_t)n*D + lane*2;
  float x0 = A[base]   + B[base];
  float x1 = A[base+1] + B[base+1];
  float s = x0 + x1;
  #pragma unroll
  for (int off = 1; off < 64; off <<= 1) s += __shfl_xor(s, off);
  float mu = s * (1.0f/128.0f);
  float d0 = x0 - mu, d1 = x1 - mu;
  float ss = d0*d0 + d1*d1;
  #pragma unroll
  for (int off = 1; off < 64; off <<= 1) ss += __shfl_xor(ss, off);
  float r = rsqrtf(ss * (1.0f/128.0f) + LN_EPS);
  float o0 = d0*r*g[lane*2]   + bb[lane*2];
  float o1 = d1*r*g[lane*2+1] + bb[lane*2+1];
  out[base]    = o0;
  out[base+1]  = o1;
  outb[base]   = f2bf(o0);
  outb[base+1] = f2bf(o1);
}

// ---------------- decoder + mean ----------------
__global__ __launch_bounds__(256) void dec_partial(const float* __restrict__ h,
    const float* __restrict__ W, float* __restrict__ partials, int N)
{
  float acc = 0.f;
  for (int n = blockIdx.x*256 + threadIdx.x; n < N; n += 256*256) {
    const float* hr = h + (size_t)n*D;
    float s = 0.f;
    #pragma unroll
    for (int t = 0; t < 32; t++) {
      float4 hv = ld4(&hr[t*4]); float4 wv = ld4(&W[t*4]);
      s += hv.x*wv.x + hv.y*wv.y + hv.z*wv.z + hv.w*wv.w;
    }
    acc += s;
  }
  #pragma unroll
  for (int off = 1; off < 64; off <<= 1) acc += __shfl_xor(acc, off);
  __shared__ float red[4];
  int lane = threadIdx.x & 63, w = threadIdx.x >> 6;
  if (lane == 0) red[w] = acc;
  __syncthreads();
  if (threadIdx.x == 0) partials[blockIdx.x] = red[0]+red[1]+red[2]+red[3];
}

__global__ __launch_bounds__(256) void dec_final(const float* __restrict__ partials,
    const float* __restrict__ decb, float* __restrict__ out, int N)
{
  float a = partials[threadIdx.x];
  #pragma unroll
  for (int off = 1; off < 64; off <<= 1) a += __shfl_xor(a, off);
  __shared__ float red[4];
  int lane = threadIdx.x & 63, w = threadIdx.x >> 6;
  if (lane == 0) red[w] = a;
  __syncthreads();
  if (threadIdx.x == 0) out[0] = (red[0]+red[1]+red[2]+red[3]) / (float)N + decb[0];
}

// ---------------- launch ----------------
extern "C" void kernel_launch(void* const* d_in, const int* in_sizes, int n_in,
                              void* d_out, int out_size, void* d_ws, size_t ws_size,
                              hipStream_t stream)
{
  const float* nf   = (const float*)d_in[0];
  const int*   src  = (const int*)  d_in[1];
  const int*   dst  = (const int*)  d_in[2];
  const float* encW = (const float*)d_in[3];
  const float* encb = (const float*)d_in[4];
  const float* Wq   = (const float*)d_in[5];
  const float* Wk   = (const float*)d_in[6];
  const float* Wv   = (const float*)d_in[7];
  const float* Wo   = (const float*)d_in[8];
  const float* ln1g = (const float*)d_in[9];
  const float* ln1b = (const float*)d_in[10];
  const float* W1   = (const float*)d_in[11];
  const float* b1   = (const float*)d_in[12];
  const float* W2   = (const float*)d_in[13];
  const float* b2   = (const float*)d_in[14];
  const float* ln2g = (const float*)d_in[15];
  const float* ln2b = (const float*)d_in[16];
  const float* decW = (const float*)d_in[17];
  const float* decb = (const float*)d_in[18];
  float* out = (float*)d_out;

  const int N = in_sizes[0] / 16;
  const int E = in_sizes[1];

  float* ws   = (float*)d_ws;
  float* h    = ws;                              // [N,128] f32
  float* h1   = h  + (size_t)N*128;              // [N,128] f32
  float* q    = h1 + (size_t)N*128;              // [N,128] f32 (also uh / ffn2-out)
  u16*  hb    = (u16*)(q + (size_t)N*128);       // [N,128] bf16
  u16*  h1b   = hb  + (size_t)N*128;             // [N,128] bf16
  u16*  kvb   = h1b + (size_t)N*128;             // [N,256] bf16 (k | v)
  u16*  savb  = kvb + (size_t)N*256;             // [N,128] bf16 (attn out)
  u16*  fbb   = savb + (size_t)N*128;            // [N,512] bf16 (ffn hidden)
  float* ubuf = (float*)(fbb + (size_t)N*512);   // [E,8] f32
  int* deg    = (int*)(ubuf + (size_t)E*8);
  int* offs   = deg + N;
  int* cursor = offs + N + 1;
  int* csr    = cursor + N;
  float* partials = (float*)(csr + E);
  u16* wbuf   = (u16*)(partials + 512);          // bf16 weights: 589824
  u16* wqkv   = wbuf;                            // [3][384][128]
  u16* wo_b   = wbuf + 147456;                   // [3][128][128]
  u16* w1_b   = wbuf + 196608;                   // [3][512][128]
  u16* w2_b   = wbuf + 393216;                   // [3][128][512]

  // CSR build (dst -> incoming edge list)
  hipMemsetAsync(deg, 0, sizeof(int)*N, stream);
  count_kernel<<<(E+255)/256, 256, 0, stream>>>(dst, deg, E);
  scan_kernel<<<1, 1024, 0, stream>>>(deg, offs, cursor, N);
  fill_kernel<<<(E+255)/256, 256, 0, stream>>>(dst, cursor, csr, E);

  convert_weights<<<(589824+255)/256, 256, 0, stream>>>(Wq, Wk, Wv, Wo, W1, W2, wbuf);

  encoder_kernel<<<(N+1)/2, 256, 0, stream>>>(nf, encW, encb, h, hb, N);

  const int gmx = (N + 127)/128;
  for (int l = 0; l < LAYERS; l++) {
    const u16* wqkv_l = wqkv + (size_t)l*384*128;
    const u16* wo_l   = wo_b + (size_t)l*128*128;
    const u16* w1_l   = w1_b + (size_t)l*512*128;
    const u16* w2_l   = w2_b + (size_t)l*128*512;

    // q (f32 out) and k|v (bf16 out)
    gemm_mfma<128,false,false><<<dim3(gmx,1), 256, 0, stream>>>(
        hb, wqkv_l, nullptr, q, nullptr, N, 128);
    gemm_mfma<128,false,true><<<dim3(gmx,2), 256, 0, stream>>>(
        hb, wqkv_l + 128*128, nullptr, nullptr, kvb, N, 256);

    attn_kernel<<<(N+15)/16, 256, 0, stream>>>(q, kvb, src, offs, csr, ubuf, savb, N);

    // uh = sum_av @ Wo^T  (reuse q buffer as f32 uh)
    gemm_mfma<128,false,false><<<dim3(gmx,1), 256, 0, stream>>>(
        savb, wo_l, nullptr, q, nullptr, N, 128);

    add_ln_kernel<<<(N+3)/4, 256, 0, stream>>>(h, q, ln1g + l*D, ln1b + l*D, h1, h1b, N);

    gemm_mfma<128,true,true><<<dim3(gmx,4), 256, 0, stream>>>(
        h1b, w1_l, b1 + l*DFF, nullptr, fbb, N, 512);

    gemm_mfma<512,false,false><<<dim3(gmx,1), 256, 0, stream>>>(
        fbb, w2_l, b2 + l*D, q, nullptr, N, 128);

    add_ln_kernel<<<(N+3)/4, 256, 0, stream>>>(h1, q, ln2g + l*D, ln2b + l*D, h, hb, N);
  }

  dec_partial<<<256, 256, 0, stream>>>(h, decW, partials, N);
  dec_final<<<1, 256, 0, stream>>>(partials, decb, out, N);
}

// Round 3
// 849.439 us; speedup vs baseline: 2.7173x; 1.3070x over previous
//
#include <hip/hip_runtime.h>
#include <math.h>

static constexpr int D   = 128;
static constexpr int DFF = 512;
static constexpr int LAYERS = 3;
static constexpr float CLAMP_V = 5.0f;
static constexpr float LN_EPS = 1e-5f;

typedef unsigned short u16;
typedef unsigned int   u32;
typedef short bf16x8 __attribute__((ext_vector_type(8)));
typedef float f32x4  __attribute__((ext_vector_type(4)));

__device__ inline float4 ld4(const float* p){ return *reinterpret_cast<const float4*>(p); }
__device__ inline u16 f2bf(float f){ u32 u = __float_as_uint(f); return (u16)((u + 0x7fff + ((u>>16)&1)) >> 16); }
__device__ inline float bl(u32 u){ return __uint_as_float(u << 16); }
__device__ inline float bh(u32 u){ return __uint_as_float(u & 0xffff0000u); }

__device__ inline void gload_lds16(const void* g, void* l) {
  __builtin_amdgcn_global_load_lds(
      (const __attribute__((address_space(1))) void*)g,
      (__attribute__((address_space(3))) void*)l, 16, 0, 0);
}

// ---------------- CSR build ----------------
__global__ __launch_bounds__(256) void count_kernel(const int* __restrict__ dst,
                                                    int* __restrict__ deg, int E)
{
  int e = blockIdx.x*256 + threadIdx.x;
  if (e < E) atomicAdd(&deg[dst[e]], 1);
}

__global__ __launch_bounds__(1024) void scan_kernel(const int* __restrict__ deg,
    int* __restrict__ offs, int* __restrict__ cursor, int N)
{
  __shared__ int lds[1024];
  const int tid = threadIdx.x;
  const int C = (N + 1023) >> 10;
  const int lo = tid * C;
  const int hi = (lo + C < N) ? (lo + C) : N;
  int ss = 0;
  for (int n = lo; n < hi; n++) ss += deg[n];
  lds[tid] = ss;
  __syncthreads();
  for (int off = 1; off < 1024; off <<= 1) {
    int vv = (tid >= off) ? lds[tid - off] : 0;
    __syncthreads();
    lds[tid] += vv;
    __syncthreads();
  }
  int run = (tid == 0) ? 0 : lds[tid - 1];
  for (int n = lo; n < hi; n++) { offs[n] = run; cursor[n] = run; run += deg[n]; }
  if (tid == 1023) offs[N] = lds[1023];
}

__global__ __launch_bounds__(256) void fill_kernel(const int* __restrict__ dst,
    int* __restrict__ cursor, int* __restrict__ csr, int E)
{
  int e = blockIdx.x*256 + threadIdx.x;
  if (e < E) {
    int p = atomicAdd(&cursor[dst[e]], 1);
    csr[p] = e;
  }
}

// ---------------- weight conversion to bf16 ----------------
__global__ __launch_bounds__(256) void convert_weights(
    const float* __restrict__ Wq, const float* __restrict__ Wk, const float* __restrict__ Wv,
    const float* __restrict__ Wo, const float* __restrict__ W1, const float* __restrict__ W2,
    u16* __restrict__ out)
{
  const int SQKV = 3*384*128;
  const int SWO  = 3*128*128;
  const int SW1  = 3*512*128;
  const int SW2  = 3*128*512;
  int i = blockIdx.x*256 + threadIdx.x;
  if (i >= SQKV+SWO+SW1+SW2) return;
  float v;
  if (i < SQKV) {
    int l = i / (384*128), rem = i % (384*128);
    int row = rem / 128, col = rem % 128;
    const float* W = (row < 128) ? Wq : ((row < 256) ? Wk : Wv);
    v = W[(size_t)l*128*128 + (size_t)(row & 127)*128 + col];
  } else if (i < SQKV+SWO) {
    v = Wo[i - SQKV];
  } else if (i < SQKV+SWO+SW1) {
    v = W1[i - SQKV - SWO];
  } else {
    v = W2[i - SQKV - SWO - SW1];
  }
  out[i] = f2bf(v);
}

// ---------------- encoder (f32 + bf16 dual write) ----------------
__global__ __launch_bounds__(256) void encoder_kernel(
    const float* __restrict__ nf, const float* __restrict__ W,
    const float* __restrict__ b, float* __restrict__ h, u16* __restrict__ hb, int N)
{
  int n = blockIdx.x*2 + (threadIdx.x >> 7);
  int d = threadIdx.x & 127;
  if (n >= N) return;
  const float* nr = nf + (size_t)n*16;
  const float* wr = W  + (size_t)d*16;
  float s = b[d];
  #pragma unroll
  for (int kk = 0; kk < 16; kk++) s = fmaf(nr[kk], wr[kk], s);
  h[(size_t)n*D + d]  = s;
  hb[(size_t)n*D + d] = f2bf(s);
}

// ---------------- shared MFMA GEMM core: 128x128 tile, acc = A*B^T ----------------
template<int K>
__device__ inline void gemm_core(const u16* __restrict__ A, const u16* __restrict__ B,
                                 int M, int m0, u16* lA, u16* lB, f32x4 acc[4][4])
{
  const int tid  = threadIdx.x;
  const int lane = tid & 63;
  const int wid  = tid >> 6;
  const int wr   = wid >> 1, wc = wid & 1;

  const int ldrow = lane >> 3;
  const int gran  = (lane & 7) ^ ldrow;

  #pragma unroll
  for (int ks = 0; ks < K/64; ks++) {
    __syncthreads();
    const int k0 = ks*64 + gran*8;
    #pragma unroll
    for (int is = 0; is < 4; is++) {
      const int r  = wid*32 + is*8;
      int gm = m0 + r + ldrow; if (gm >= M) gm = M - 1;
      gload_lds16(A + (size_t)gm*K + k0, &lA[r*64]);
      gload_lds16(B + (size_t)(r + ldrow)*K + k0, &lB[r*64]);
    }
    asm volatile("s_waitcnt vmcnt(0)" ::: "memory");
    __syncthreads();

    #pragma unroll
    for (int k2 = 0; k2 < 2; k2++) {
      bf16x8 af[4], bfr[4];
      const int kq = k2*4 + (lane >> 4);
      #pragma unroll
      for (int mi = 0; mi < 4; mi++) {
        const int r = wr*64 + mi*16 + (lane & 15);
        af[mi] = *(const bf16x8*)&lA[r*64 + ((kq ^ (r & 7)) << 3)];
      }
      #pragma unroll
      for (int ni = 0; ni < 4; ni++) {
        const int r = wc*64 + ni*16 + (lane & 15);
        bfr[ni] = *(const bf16x8*)&lB[r*64 + ((kq ^ (r & 7)) << 3)];
      }
      #pragma unroll
      for (int mi = 0; mi < 4; mi++)
        #pragma unroll
        for (int ni = 0; ni < 4; ni++)
          acc[mi][ni] = __builtin_amdgcn_mfma_f32_16x16x32_bf16(af[mi], bfr[ni], acc[mi][ni], 0, 0, 0);
    }
  }
}

// ---------------- QKV GEMM: y=0 -> q (f32), y=1,2 -> kvb (bf16, ldc 256) ----------------
__global__ __launch_bounds__(256) void gemm_qkv(
    const u16* __restrict__ A, const u16* __restrict__ B,
    float* __restrict__ qf, u16* __restrict__ kvb, int M)
{
  __shared__ u16 lA[128*64];
  __shared__ u16 lB[128*64];
  const int s  = blockIdx.y;
  const int m0 = blockIdx.x * 128;
  f32x4 acc[4][4];
  #pragma unroll
  for (int i = 0; i < 4; i++)
    #pragma unroll
    for (int j = 0; j < 4; j++) { acc[i][j][0]=0.f; acc[i][j][1]=0.f; acc[i][j][2]=0.f; acc[i][j][3]=0.f; }

  gemm_core<128>(A, B + (size_t)s*128*128, M, m0, lA, lB, acc);

  const int lane  = threadIdx.x & 63;
  const int wid   = threadIdx.x >> 6;
  const int wr    = wid >> 1, wc = wid & 1;
  const int rbase = m0 + wr*64 + ((lane >> 4) << 2);
  const int cbase = wc*64 + (lane & 15);
  #pragma unroll
  for (int ni = 0; ni < 4; ni++) {
    const int col = cbase + ni*16;
    #pragma unroll
    for (int mi = 0; mi < 4; mi++) {
      #pragma unroll
      for (int r = 0; r < 4; r++) {
        const int gm = rbase + mi*16 + r;
        if (gm < M) {
          if (s == 0) qf[(size_t)gm*128 + col] = acc[mi][ni][r];
          else        kvb[(size_t)gm*256 + (s-1)*128 + col] = f2bf(acc[mi][ni][r]);
        }
      }
    }
  }
}

// ---------------- FFN1 GEMM: bias + relu, bf16 out ldc=512, y in 0..3 ----------------
__global__ __launch_bounds__(256) void gemm_relu(
    const u16* __restrict__ A, const u16* __restrict__ B, const float* __restrict__ bias,
    u16* __restrict__ Cb, int M)
{
  __shared__ u16 lA[128*64];
  __shared__ u16 lB[128*64];
  const int f0 = blockIdx.y * 128;
  const int m0 = blockIdx.x * 128;
  f32x4 acc[4][4];
  #pragma unroll
  for (int i = 0; i < 4; i++)
    #pragma unroll
    for (int j = 0; j < 4; j++) { acc[i][j][0]=0.f; acc[i][j][1]=0.f; acc[i][j][2]=0.f; acc[i][j][3]=0.f; }

  gemm_core<128>(A, B + (size_t)f0*128, M, m0, lA, lB, acc);

  const int lane  = threadIdx.x & 63;
  const int wid   = threadIdx.x >> 6;
  const int wr    = wid >> 1, wc = wid & 1;
  const int rbase = m0 + wr*64 + ((lane >> 4) << 2);
  const int cbase = wc*64 + (lane & 15);
  #pragma unroll
  for (int ni = 0; ni < 4; ni++) {
    const int col = cbase + ni*16;
    const float bv = bias[f0 + col];
    #pragma unroll
    for (int mi = 0; mi < 4; mi++) {
      #pragma unroll
      for (int r = 0; r < 4; r++) {
        const int gm = rbase + mi*16 + r;
        if (gm < M) Cb[(size_t)gm*512 + f0 + col] = f2bf(fmaxf(acc[mi][ni][r] + bv, 0.f));
      }
    }
  }
}

// ---------------- GEMM + residual + LayerNorm fused (F=128) ----------------
// out = LN(res + A@B^T + bias) * g + bb ; writes f32 + bf16
template<int K>
__global__ __launch_bounds__(256) void gemm_ln(
    const u16* __restrict__ A, const u16* __restrict__ B, const float* __restrict__ bias,
    const float* __restrict__ res, const float* __restrict__ g, const float* __restrict__ bb,
    float* __restrict__ Of, u16* __restrict__ Ob, int M)
{
  __shared__ u16 lA[128*64];
  __shared__ u16 lB[128*64];
  __shared__ float lsum[128][2];
  __shared__ float lsq[128][2];
  const int m0 = blockIdx.x * 128;
  f32x4 acc[4][4];
  #pragma unroll
  for (int i = 0; i < 4; i++)
    #pragma unroll
    for (int j = 0; j < 4; j++) { acc[i][j][0]=0.f; acc[i][j][1]=0.f; acc[i][j][2]=0.f; acc[i][j][3]=0.f; }

  gemm_core<K>(A, B, M, m0, lA, lB, acc);

  const int lane = threadIdx.x & 63;
  const int wid  = threadIdx.x >> 6;
  const int wr   = wid >> 1, wc = wid & 1;
  const int rl0  = wr*64 + ((lane >> 4) << 2);
  const int cl   = wc*64 + (lane & 15);

  // pass 1: row partial sums over this wave's 64 cols
  #pragma unroll
  for (int mi = 0; mi < 4; mi++) {
    #pragma unroll
    for (int r = 0; r < 4; r++) {
      const int lrow = rl0 + mi*16 + r;
      int gr = m0 + lrow; if (gr >= M) gr = M - 1;
      float ps = 0.f, pq = 0.f;
      #pragma unroll
      for (int ni = 0; ni < 4; ni++) {
        const int col = cl + ni*16;
        float x = acc[mi][ni][r] + (bias ? bias[col] : 0.f) + res[(size_t)gr*128 + col];
        ps += x; pq += x*x;
      }
      #pragma unroll
      for (int off = 1; off < 16; off <<= 1) {
        ps += __shfl_xor(ps, off);
        pq += __shfl_xor(pq, off);
      }
      if ((lane & 15) == 0) { lsum[lrow][wc] = ps; lsq[lrow][wc] = pq; }
    }
  }
  __syncthreads();

  // pass 2: normalize + write
  #pragma unroll
  for (int mi = 0; mi < 4; mi++) {
    #pragma unroll
    for (int r = 0; r < 4; r++) {
      const int lrow = rl0 + mi*16 + r;
      const int grow = m0 + lrow;
      if (grow >= M) continue;
      const float mean = (lsum[lrow][0] + lsum[lrow][1]) * (1.0f/128.0f);
      float var = (lsq[lrow][0] + lsq[lrow][1]) * (1.0f/128.0f) - mean*mean;
      const float rstd = rsqrtf(fmaxf(var, 0.f) + LN_EPS);
      #pragma unroll
      for (int ni = 0; ni < 4; ni++) {
        const int col = cl + ni*16;
        float x = acc[mi][ni][r] + (bias ? bias[col] : 0.f) + res[(size_t)grow*128 + col];
        float o = (x - mean) * rstd * g[col] + bb[col];
        Of[(size_t)grow*128 + col] = o;
        Ob[(size_t)grow*128 + col] = f2bf(o);
      }
    }
  }
}

// ---------------- attention: single-pass, constant-shift softmax ----------------
// 16 lanes per node; lane j owns output elems j*8..j*8+7 (head j>>1).
__global__ __launch_bounds__(256) void attn_kernel(
    const float* __restrict__ q, const u16* __restrict__ kv,
    const int* __restrict__ src,
    const int* __restrict__ offs, const int* __restrict__ csr,
    u16* __restrict__ outb, int N)
{
  const int tid = threadIdx.x;
  const int j   = tid & 15;
  const int n   = blockIdx.x*16 + (tid >> 4);
  if (n >= N) return;

  float qreg[8];
  *(float4*)&qreg[0] = ld4(&q[(size_t)n*128 + j*8]);
  *(float4*)&qreg[4] = ld4(&q[(size_t)n*128 + j*8 + 4]);

  const int start = offs[n];
  const int deg   = offs[n+1] - start;

  float s = 0.f;
  float acc[8] = {0,0,0,0,0,0,0,0};
  const int gb = tid & 48;   // group base within wave

  for (int base = 0; base < deg; base += 16) {
    const int myidx = base + j;
    const int sn_mine = (myidx < deg) ? src[csr[start + myidx]] : 0;
    const int cnt = (deg - base < 16) ? (deg - base) : 16;

    for (int b2 = 0; b2 < cnt; b2 += 4) {
      const int m4 = cnt - b2;
      uint4 K4[4], V4[4];
      #pragma unroll
      for (int u = 0; u < 4; u++) {
        const int sel = b2 + ((u < m4) ? u : 0);
        const int sn = __shfl(sn_mine, gb + sel);
        const u16* row = kv + (size_t)sn*256 + j*8;
        K4[u] = *(const uint4*)row;
        V4[u] = *(const uint4*)(row + 128);
      }
      #pragma unroll
      for (int u = 0; u < 4; u++) {
        if (u < m4) {
          float d = bl(K4[u].x)*qreg[0] + bh(K4[u].x)*qreg[1]
                  + bl(K4[u].y)*qreg[2] + bh(K4[u].y)*qreg[3]
                  + bl(K4[u].z)*qreg[4] + bh(K4[u].z)*qreg[5]
                  + bl(K4[u].w)*qreg[6] + bh(K4[u].w)*qreg[7];
          d += __shfl_xor(d, 1);
          float uu = fminf(fmaxf(d * 0.25f, -CLAMP_V), CLAMP_V);
          float e = __expf(uu - CLAMP_V);
          s += e;
          acc[0] = fmaf(e, bl(V4[u].x), acc[0]);
          acc[1] = fmaf(e, bh(V4[u].x), acc[1]);
          acc[2] = fmaf(e, bl(V4[u].y), acc[2]);
          acc[3] = fmaf(e, bh(V4[u].y), acc[3]);
          acc[4] = fmaf(e, bl(V4[u].z), acc[4]);
          acc[5] = fmaf(e, bh(V4[u].z), acc[5]);
          acc[6] = fmaf(e, bl(V4[u].w), acc[6]);
          acc[7] = fmaf(e, bh(V4[u].w), acc[7]);
        }
      }
    }
  }

  const float rs = (deg > 0) ? (1.0f / s) : 0.f;
  u16 o[8];
  #pragma unroll
  for (int t = 0; t < 8; t++) o[t] = f2bf(acc[t] * rs);
  *(uint4*)&outb[(size_t)n*128 + j*8] = *(const uint4*)o;
}

// ---------------- decoder + mean ----------------
__global__ __launch_bounds__(256) void dec_partial(const float* __restrict__ h,
    const float* __restrict__ W, float* __restrict__ partials, int N)
{
  float acc = 0.f;
  for (int n = blockIdx.x*256 + threadIdx.x; n < N; n += 256*256) {
    const float* hr = h + (size_t)n*D;
    float s = 0.f;
    #pragma unroll
    for (int t = 0; t < 32; t++) {
      float4 hv = ld4(&hr[t*4]); float4 wv = ld4(&W[t*4]);
      s += hv.x*wv.x + hv.y*wv.y + hv.z*wv.z + hv.w*wv.w;
    }
    acc += s;
  }
  #pragma unroll
  for (int off = 1; off < 64; off <<= 1) acc += __shfl_xor(acc, off);
  __shared__ float red[4];
  int lane = threadIdx.x & 63, w = threadIdx.x >> 6;
  if (lane == 0) red[w] = acc;
  __syncthreads();
  if (threadIdx.x == 0) partials[blockIdx.x] = red[0]+red[1]+red[2]+red[3];
}

__global__ __launch_bounds__(256) void dec_final(const float* __restrict__ partials,
    const float* __restrict__ decb, float* __restrict__ out, int N)
{
  float a = partials[threadIdx.x];
  #pragma unroll
  for (int off = 1; off < 64; off <<= 1) a += __shfl_xor(a, off);
  __shared__ float red[4];
  int lane = threadIdx.x & 63, w = threadIdx.x >> 6;
  if (lane == 0) red[w] = a;
  __syncthreads();
  if (threadIdx.x == 0) out[0] = (red[0]+red[1]+red[2]+red[3]) / (float)N + decb[0];
}

// ---------------- launch ----------------
extern "C" void kernel_launch(void* const* d_in, const int* in_sizes, int n_in,
                              void* d_out, int out_size, void* d_ws, size_t ws_size,
                              hipStream_t stream)
{
  const float* nf   = (const float*)d_in[0];
  const int*   src  = (const int*)  d_in[1];
  const int*   dst  = (const int*)  d_in[2];
  const float* encW = (const float*)d_in[3];
  const float* encb = (const float*)d_in[4];
  const float* Wq   = (const float*)d_in[5];
  const float* Wk   = (const float*)d_in[6];
  const float* Wv   = (const float*)d_in[7];
  const float* Wo   = (const float*)d_in[8];
  const float* ln1g = (const float*)d_in[9];
  const float* ln1b = (const float*)d_in[10];
  const float* W1   = (const float*)d_in[11];
  const float* b1   = (const float*)d_in[12];
  const float* W2   = (const float*)d_in[13];
  const float* b2   = (const float*)d_in[14];
  const float* ln2g = (const float*)d_in[15];
  const float* ln2b = (const float*)d_in[16];
  const float* decW = (const float*)d_in[17];
  const float* decb = (const float*)d_in[18];
  float* out = (float*)d_out;

  const int N = in_sizes[0] / 16;
  const int E = in_sizes[1];

  float* ws   = (float*)d_ws;
  float* h    = ws;                              // [N,128] f32
  float* h1   = h  + (size_t)N*128;              // [N,128] f32
  float* q    = h1 + (size_t)N*128;              // [N,128] f32
  u16*  hb    = (u16*)(q + (size_t)N*128);       // [N,128] bf16
  u16*  h1b   = hb  + (size_t)N*128;             // [N,128] bf16
  u16*  kvb   = h1b + (size_t)N*128;             // [N,256] bf16 (k | v)
  u16*  savb  = kvb + (size_t)N*256;             // [N,128] bf16 (attn out)
  u16*  fbb   = savb + (size_t)N*128;            // [N,512] bf16 (ffn hidden)
  int* deg    = (int*)(fbb + (size_t)N*512);
  int* offs   = deg + N;
  int* cursor = offs + N + 1;
  int* csr    = cursor + N;
  float* partials = (float*)(csr + E);
  u16* wbuf   = (u16*)(partials + 512);          // bf16 weights
  u16* wqkv   = wbuf;                            // [3][384][128]
  u16* wo_b   = wbuf + 147456;                   // [3][128][128]
  u16* w1_b   = wbuf + 196608;                   // [3][512][128]
  u16* w2_b   = wbuf + 393216;                   // [3][128][512]

  hipMemsetAsync(deg, 0, sizeof(int)*N, stream);
  count_kernel<<<(E+255)/256, 256, 0, stream>>>(dst, deg, E);
  scan_kernel<<<1, 1024, 0, stream>>>(deg, offs, cursor, N);
  fill_kernel<<<(E+255)/256, 256, 0, stream>>>(dst, cursor, csr, E);

  convert_weights<<<(589824+255)/256, 256, 0, stream>>>(Wq, Wk, Wv, Wo, W1, W2, wbuf);

  encoder_kernel<<<(N+1)/2, 256, 0, stream>>>(nf, encW, encb, h, hb, N);

  const int gmx = (N + 127)/128;
  for (int l = 0; l < LAYERS; l++) {
    const u16* wqkv_l = wqkv + (size_t)l*384*128;
    const u16* wo_l   = wo_b + (size_t)l*128*128;
    const u16* w1_l   = w1_b + (size_t)l*512*128;
    const u16* w2_l   = w2_b + (size_t)l*128*512;

    gemm_qkv<<<dim3(gmx,3), 256, 0, stream>>>(hb, wqkv_l, q, kvb, N);

    attn_kernel<<<(N+15)/16, 256, 0, stream>>>(q, kvb, src, offs, csr, savb, N);

    // h1 = LN(h + savb@Wo^T)  (fused)
    gemm_ln<128><<<dim3(gmx,1), 256, 0, stream>>>(
        savb, wo_l, nullptr, h, ln1g + l*D, ln1b + l*D, h1, h1b, N);

    gemm_relu<<<dim3(gmx,4), 256, 0, stream>>>(h1b, w1_l, b1 + l*DFF, fbb, N);

    // h = LN(h1 + fbb@W2^T + b2)  (fused)
    gemm_ln<512><<<dim3(gmx,1), 256, 0, stream>>>(
        fbb, w2_l, b2 + l*D, h1, ln2g + l*D, ln2b + l*D, h, hb, N);
  }

  dec_partial<<<256, 256, 0, stream>>>(h, decW, partials, N);
  dec_final<<<1, 256, 0, stream>>>(partials, decb, out, N);
}

// Round 4
// 717.952 us; speedup vs baseline: 3.2149x; 1.1831x over previous
//
#include <hip/hip_runtime.h>
#include <math.h>

static constexpr int D   = 128;
static constexpr int DFF = 512;
static constexpr int LAYERS = 3;
static constexpr float CLAMP_V = 5.0f;
static constexpr float LN_EPS = 1e-5f;

typedef unsigned short u16;
typedef unsigned int   u32;
typedef short bf16x8 __attribute__((ext_vector_type(8)));
typedef float f32x4  __attribute__((ext_vector_type(4)));

__device__ inline float4 ld4(const float* p){ return *reinterpret_cast<const float4*>(p); }
__device__ inline u16 f2bf(float f){ u32 u = __float_as_uint(f); return (u16)((u + 0x7fff + ((u>>16)&1)) >> 16); }
__device__ inline float bl(u32 u){ return __uint_as_float(u << 16); }
__device__ inline float bh(u32 u){ return __uint_as_float(u & 0xffff0000u); }

__device__ inline void gload_lds16(const void* g, void* l) {
  __builtin_amdgcn_global_load_lds(
      (const __attribute__((address_space(1))) void*)g,
      (__attribute__((address_space(3))) void*)l, 16, 0, 0);
}

// ---------------- CSR build ----------------
__global__ __launch_bounds__(256) void count_kernel(const int* __restrict__ dst,
                                                    int* __restrict__ deg, int E)
{
  int e = blockIdx.x*256 + threadIdx.x;
  if (e < E) atomicAdd(&deg[dst[e]], 1);
}

// per-1024-chunk sums
__global__ __launch_bounds__(256) void scan_bsum(const int* __restrict__ deg,
                                                 int* __restrict__ bsum, int N)
{
  const int i0 = blockIdx.x*1024 + threadIdx.x*4;
  int s = 0;
  if (i0 + 3 < N) { int4 v = *(const int4*)&deg[i0]; s = v.x+v.y+v.z+v.w; }
  else { for (int t = 0; t < 4; t++) if (i0+t < N) s += deg[i0+t]; }
  #pragma unroll
  for (int off = 1; off < 64; off <<= 1) s += __shfl_xor(s, off);
  __shared__ int ws_[4];
  if ((threadIdx.x & 63) == 0) ws_[threadIdx.x >> 6] = s;
  __syncthreads();
  if (threadIdx.x == 0) bsum[blockIdx.x] = ws_[0]+ws_[1]+ws_[2]+ws_[3];
}

// exclusive scan of block sums (single wave, chunked)
__global__ __launch_bounds__(64) void scan_bbase(int* __restrict__ bsum, int NB)
{
  const int tid = threadIdx.x;
  int base = 0;
  for (int c = 0; c < NB; c += 64) {
    const int idx = c + tid;
    int v = (idx < NB) ? bsum[idx] : 0;
    const int orig = v;
    #pragma unroll
    for (int off = 1; off < 64; off <<= 1) {
      int t = __shfl_up(v, off);
      if (tid >= off) v += t;
    }
    if (idx < NB) bsum[idx] = base + v - orig;
    base += __shfl(v, 63);
  }
}

// block-local exclusive scan + write offs/cursor
__global__ __launch_bounds__(256) void scan_write(const int* __restrict__ deg,
    const int* __restrict__ bbase, int* __restrict__ offs, int* __restrict__ cursor, int N)
{
  const int i0 = blockIdx.x*1024 + threadIdx.x*4;
  int v[4] = {0,0,0,0};
  if (i0 + 3 < N) { int4 t = *(const int4*)&deg[i0]; v[0]=t.x; v[1]=t.y; v[2]=t.z; v[3]=t.w; }
  else { for (int t = 0; t < 4; t++) if (i0+t < N) v[t] = deg[i0+t]; }
  const int s = v[0]+v[1]+v[2]+v[3];
  const int lane = threadIdx.x & 63, w = threadIdx.x >> 6;
  int inc = s;
  #pragma unroll
  for (int off = 1; off < 64; off <<= 1) {
    int t = __shfl_up(inc, off);
    if (lane >= off) inc += t;
  }
  __shared__ int wsum[4];
  if (lane == 63) wsum[w] = inc;
  __syncthreads();
  int wb = 0;
  for (int t = 0; t < 4; t++) if (t < w) wb += wsum[t];
  int run = bbase[blockIdx.x] + wb + inc - s;
  #pragma unroll
  for (int t = 0; t < 4; t++) {
    if (i0 + t < N) { offs[i0+t] = run; cursor[i0+t] = run; run += v[t]; }
  }
  if (i0 <= N-1 && N-1 < i0+4) offs[N] = run;
}

// stores SRC NODE id (not edge id) -> one less gather level in attn
__global__ __launch_bounds__(256) void fill_kernel(const int* __restrict__ dst,
    const int* __restrict__ src, int* __restrict__ cursor, int* __restrict__ csr_src, int E)
{
  int e = blockIdx.x*256 + threadIdx.x;
  if (e < E) {
    int p = atomicAdd(&cursor[dst[e]], 1);
    csr_src[p] = src[e];
  }
}

// ---------------- weight conversion to bf16 ----------------
__global__ __launch_bounds__(256) void convert_weights(
    const float* __restrict__ Wq, const float* __restrict__ Wk, const float* __restrict__ Wv,
    const float* __restrict__ Wo, const float* __restrict__ W1, const float* __restrict__ W2,
    u16* __restrict__ out)
{
  const int SQKV = 3*384*128;
  const int SWO  = 3*128*128;
  const int SW1  = 3*512*128;
  const int SW2  = 3*128*512;
  int i = blockIdx.x*256 + threadIdx.x;
  if (i >= SQKV+SWO+SW1+SW2) return;
  float v;
  if (i < SQKV) {
    int l = i / (384*128), rem = i % (384*128);
    int row = rem / 128, col = rem % 128;
    const float* W = (row < 128) ? Wq : ((row < 256) ? Wk : Wv);
    v = W[(size_t)l*128*128 + (size_t)(row & 127)*128 + col];
  } else if (i < SQKV+SWO) {
    v = Wo[i - SQKV];
  } else if (i < SQKV+SWO+SW1) {
    v = W1[i - SQKV - SWO];
  } else {
    v = W2[i - SQKV - SWO - SW1];
  }
  out[i] = f2bf(v);
}

// ---------------- encoder (f32 + bf16 dual write) ----------------
__global__ __launch_bounds__(256) void encoder_kernel(
    const float* __restrict__ nf, const float* __restrict__ W,
    const float* __restrict__ b, float* __restrict__ h, u16* __restrict__ hb, int N)
{
  int n = blockIdx.x*2 + (threadIdx.x >> 7);
  int d = threadIdx.x & 127;
  if (n >= N) return;
  const float* nr = nf + (size_t)n*16;
  const float* wr = W  + (size_t)d*16;
  float s = b[d];
  #pragma unroll
  for (int kk = 0; kk < 16; kk++) s = fmaf(nr[kk], wr[kk], s);
  h[(size_t)n*D + d]  = s;
  hb[(size_t)n*D + d] = f2bf(s);
}

// ---------------- shared MFMA GEMM core: 128x128 tile, acc = A*B^T ----------------
template<int K>
__device__ inline void gemm_core(const u16* __restrict__ A, const u16* __restrict__ B,
                                 int M, int m0, u16* lA, u16* lB, f32x4 acc[4][4])
{
  const int tid  = threadIdx.x;
  const int lane = tid & 63;
  const int wid  = tid >> 6;
  const int wr   = wid >> 1, wc = wid & 1;

  const int ldrow = lane >> 3;
  const int gran  = (lane & 7) ^ ldrow;

  #pragma unroll
  for (int ks = 0; ks < K/64; ks++) {
    __syncthreads();
    const int k0 = ks*64 + gran*8;
    #pragma unroll
    for (int is = 0; is < 4; is++) {
      const int r  = wid*32 + is*8;
      int gm = m0 + r + ldrow; if (gm >= M) gm = M - 1;
      gload_lds16(A + (size_t)gm*K + k0, &lA[r*64]);
      gload_lds16(B + (size_t)(r + ldrow)*K + k0, &lB[r*64]);
    }
    asm volatile("s_waitcnt vmcnt(0)" ::: "memory");
    __syncthreads();

    #pragma unroll
    for (int k2 = 0; k2 < 2; k2++) {
      bf16x8 af[4], bfr[4];
      const int kq = k2*4 + (lane >> 4);
      #pragma unroll
      for (int mi = 0; mi < 4; mi++) {
        const int r = wr*64 + mi*16 + (lane & 15);
        af[mi] = *(const bf16x8*)&lA[r*64 + ((kq ^ (r & 7)) << 3)];
      }
      #pragma unroll
      for (int ni = 0; ni < 4; ni++) {
        const int r = wc*64 + ni*16 + (lane & 15);
        bfr[ni] = *(const bf16x8*)&lB[r*64 + ((kq ^ (r & 7)) << 3)];
      }
      #pragma unroll
      for (int mi = 0; mi < 4; mi++)
        #pragma unroll
        for (int ni = 0; ni < 4; ni++)
          acc[mi][ni] = __builtin_amdgcn_mfma_f32_16x16x32_bf16(af[mi], bfr[ni], acc[mi][ni], 0, 0, 0);
    }
  }
}

// ---------------- QKV GEMM: y=0 -> q (f32), y=1,2 -> kvb (bf16, ldc 256) ----------------
__global__ __launch_bounds__(256) void gemm_qkv(
    const u16* __restrict__ A, const u16* __restrict__ B,
    float* __restrict__ qf, u16* __restrict__ kvb, int M)
{
  __shared__ u16 lA[128*64];
  __shared__ u16 lB[128*64];
  const int s  = blockIdx.y;
  const int m0 = blockIdx.x * 128;
  f32x4 acc[4][4];
  #pragma unroll
  for (int i = 0; i < 4; i++)
    #pragma unroll
    for (int j = 0; j < 4; j++) { acc[i][j][0]=0.f; acc[i][j][1]=0.f; acc[i][j][2]=0.f; acc[i][j][3]=0.f; }

  gemm_core<128>(A, B + (size_t)s*128*128, M, m0, lA, lB, acc);

  const int lane  = threadIdx.x & 63;
  const int wid   = threadIdx.x >> 6;
  const int wr    = wid >> 1, wc = wid & 1;
  const int rbase = m0 + wr*64 + ((lane >> 4) << 2);
  const int cbase = wc*64 + (lane & 15);
  #pragma unroll
  for (int ni = 0; ni < 4; ni++) {
    const int col = cbase + ni*16;
    #pragma unroll
    for (int mi = 0; mi < 4; mi++) {
      #pragma unroll
      for (int r = 0; r < 4; r++) {
        const int gm = rbase + mi*16 + r;
        if (gm < M) {
          if (s == 0) qf[(size_t)gm*128 + col] = acc[mi][ni][r];
          else        kvb[(size_t)gm*256 + (s-1)*128 + col] = f2bf(acc[mi][ni][r]);
        }
      }
    }
  }
}

// ---------------- FFN1 GEMM: bias + relu, bf16 out ldc=512, y in 0..3 ----------------
__global__ __launch_bounds__(256) void gemm_relu(
    const u16* __restrict__ A, const u16* __restrict__ B, const float* __restrict__ bias,
    u16* __restrict__ Cb, int M)
{
  __shared__ u16 lA[128*64];
  __shared__ u16 lB[128*64];
  const int f0 = blockIdx.y * 128;
  const int m0 = blockIdx.x * 128;
  f32x4 acc[4][4];
  #pragma unroll
  for (int i = 0; i < 4; i++)
    #pragma unroll
    for (int j = 0; j < 4; j++) { acc[i][j][0]=0.f; acc[i][j][1]=0.f; acc[i][j][2]=0.f; acc[i][j][3]=0.f; }

  gemm_core<128>(A, B + (size_t)f0*128, M, m0, lA, lB, acc);

  const int lane  = threadIdx.x & 63;
  const int wid   = threadIdx.x >> 6;
  const int wr    = wid >> 1, wc = wid & 1;
  const int rbase = m0 + wr*64 + ((lane >> 4) << 2);
  const int cbase = wc*64 + (lane & 15);
  #pragma unroll
  for (int ni = 0; ni < 4; ni++) {
    const int col = cbase + ni*16;
    const float bv = bias[f0 + col];
    #pragma unroll
    for (int mi = 0; mi < 4; mi++) {
      #pragma unroll
      for (int r = 0; r < 4; r++) {
        const int gm = rbase + mi*16 + r;
        if (gm < M) Cb[(size_t)gm*512 + f0 + col] = f2bf(fmaxf(acc[mi][ni][r] + bv, 0.f));
      }
    }
  }
}

// ---------------- GEMM + residual + LayerNorm fused (F=128) ----------------
template<int K>
__global__ __launch_bounds__(256) void gemm_ln(
    const u16* __restrict__ A, const u16* __restrict__ B, const float* __restrict__ bias,
    const float* __restrict__ res, const float* __restrict__ g, const float* __restrict__ bb,
    float* __restrict__ Of, u16* __restrict__ Ob, int M)
{
  __shared__ u16 lA[128*64];
  __shared__ u16 lB[128*64];
  __shared__ float lsum[128][2];
  __shared__ float lsq[128][2];
  const int m0 = blockIdx.x * 128;
  f32x4 acc[4][4];
  #pragma unroll
  for (int i = 0; i < 4; i++)
    #pragma unroll
    for (int j = 0; j < 4; j++) { acc[i][j][0]=0.f; acc[i][j][1]=0.f; acc[i][j][2]=0.f; acc[i][j][3]=0.f; }

  gemm_core<K>(A, B, M, m0, lA, lB, acc);

  const int lane = threadIdx.x & 63;
  const int wid  = threadIdx.x >> 6;
  const int wr   = wid >> 1, wc = wid & 1;
  const int rl0  = wr*64 + ((lane >> 4) << 2);
  const int cl   = wc*64 + (lane & 15);

  #pragma unroll
  for (int mi = 0; mi < 4; mi++) {
    #pragma unroll
    for (int r = 0; r < 4; r++) {
      const int lrow = rl0 + mi*16 + r;
      int gr = m0 + lrow; if (gr >= M) gr = M - 1;
      float ps = 0.f, pq = 0.f;
      #pragma unroll
      for (int ni = 0; ni < 4; ni++) {
        const int col = cl + ni*16;
        float x = acc[mi][ni][r] + (bias ? bias[col] : 0.f) + res[(size_t)gr*128 + col];
        ps += x; pq += x*x;
      }
      #pragma unroll
      for (int off = 1; off < 16; off <<= 1) {
        ps += __shfl_xor(ps, off);
        pq += __shfl_xor(pq, off);
      }
      if ((lane & 15) == 0) { lsum[lrow][wc] = ps; lsq[lrow][wc] = pq; }
    }
  }
  __syncthreads();

  #pragma unroll
  for (int mi = 0; mi < 4; mi++) {
    #pragma unroll
    for (int r = 0; r < 4; r++) {
      const int lrow = rl0 + mi*16 + r;
      const int grow = m0 + lrow;
      if (grow >= M) continue;
      const float mean = (lsum[lrow][0] + lsum[lrow][1]) * (1.0f/128.0f);
      float var = (lsq[lrow][0] + lsq[lrow][1]) * (1.0f/128.0f) - mean*mean;
      const float rstd = rsqrtf(fmaxf(var, 0.f) + LN_EPS);
      #pragma unroll
      for (int ni = 0; ni < 4; ni++) {
        const int col = cl + ni*16;
        float x = acc[mi][ni][r] + (bias ? bias[col] : 0.f) + res[(size_t)grow*128 + col];
        float o = (x - mean) * rstd * g[col] + bb[col];
        Of[(size_t)grow*128 + col] = o;
        Ob[(size_t)grow*128 + col] = f2bf(o);
      }
    }
  }
}

// ---------------- attention: single-pass, constant-shift softmax ----------------
__global__ __launch_bounds__(256) void attn_kernel(
    const float* __restrict__ q, const u16* __restrict__ kv,
    const int* __restrict__ offs, const int* __restrict__ csr_src,
    u16* __restrict__ outb, int N)
{
  const int tid = threadIdx.x;
  const int j   = tid & 15;
  const int n   = blockIdx.x*16 + (tid >> 4);
  if (n >= N) return;

  float qreg[8];
  *(float4*)&qreg[0] = ld4(&q[(size_t)n*128 + j*8]);
  *(float4*)&qreg[4] = ld4(&q[(size_t)n*128 + j*8 + 4]);

  const int start = offs[n];
  const int deg   = offs[n+1] - start;

  float s = 0.f;
  float acc[8] = {0,0,0,0,0,0,0,0};
  const int gb = tid & 48;

  for (int base = 0; base < deg; base += 16) {
    const int myidx = base + j;
    const int sn_mine = (myidx < deg) ? csr_src[start + myidx] : 0;
    const int cnt = (deg - base < 16) ? (deg - base) : 16;

    for (int b2 = 0; b2 < cnt; b2 += 4) {
      const int m4 = cnt - b2;
      uint4 K4[4], V4[4];
      #pragma unroll
      for (int u = 0; u < 4; u++) {
        const int sel = b2 + ((u < m4) ? u : 0);
        const int sn = __shfl(sn_mine, gb + sel);
        const u16* row = kv + (size_t)sn*256 + j*8;
        K4[u] = *(const uint4*)row;
        V4[u] = *(const uint4*)(row + 128);
      }
      #pragma unroll
      for (int u = 0; u < 4; u++) {
        if (u < m4) {
          float d = bl(K4[u].x)*qreg[0] + bh(K4[u].x)*qreg[1]
                  + bl(K4[u].y)*qreg[2] + bh(K4[u].y)*qreg[3]
                  + bl(K4[u].z)*qreg[4] + bh(K4[u].z)*qreg[5]
                  + bl(K4[u].w)*qreg[6] + bh(K4[u].w)*qreg[7];
          d += __shfl_xor(d, 1);
          float uu = fminf(fmaxf(d * 0.25f, -CLAMP_V), CLAMP_V);
          float e = __expf(uu - CLAMP_V);
          s += e;
          acc[0] = fmaf(e, bl(V4[u].x), acc[0]);
          acc[1] = fmaf(e, bh(V4[u].x), acc[1]);
          acc[2] = fmaf(e, bl(V4[u].y), acc[2]);
          acc[3] = fmaf(e, bh(V4[u].y), acc[3]);
          acc[4] = fmaf(e, bl(V4[u].z), acc[4]);
          acc[5] = fmaf(e, bh(V4[u].z), acc[5]);
          acc[6] = fmaf(e, bl(V4[u].w), acc[6]);
          acc[7] = fmaf(e, bh(V4[u].w), acc[7]);
        }
      }
    }
  }

  const float rs = (deg > 0) ? (1.0f / s) : 0.f;
  u16 o[8];
  #pragma unroll
  for (int t = 0; t < 8; t++) o[t] = f2bf(acc[t] * rs);
  *(uint4*)&outb[(size_t)n*128 + j*8] = *(const uint4*)o;
}

// ---------------- decoder + mean ----------------
__global__ __launch_bounds__(256) void dec_partial(const float* __restrict__ h,
    const float* __restrict__ W, float* __restrict__ partials, int N)
{
  float acc = 0.f;
  for (int n = blockIdx.x*256 + threadIdx.x; n < N; n += 256*256) {
    const float* hr = h + (size_t)n*D;
    float s = 0.f;
    #pragma unroll
    for (int t = 0; t < 32; t++) {
      float4 hv = ld4(&hr[t*4]); float4 wv = ld4(&W[t*4]);
      s += hv.x*wv.x + hv.y*wv.y + hv.z*wv.z + hv.w*wv.w;
    }
    acc += s;
  }
  #pragma unroll
  for (int off = 1; off < 64; off <<= 1) acc += __shfl_xor(acc, off);
  __shared__ float red[4];
  int lane = threadIdx.x & 63, w = threadIdx.x >> 6;
  if (lane == 0) red[w] = acc;
  __syncthreads();
  if (threadIdx.x == 0) partials[blockIdx.x] = red[0]+red[1]+red[2]+red[3];
}

__global__ __launch_bounds__(256) void dec_final(const float* __restrict__ partials,
    const float* __restrict__ decb, float* __restrict__ out, int N)
{
  float a = partials[threadIdx.x];
  #pragma unroll
  for (int off = 1; off < 64; off <<= 1) a += __shfl_xor(a, off);
  __shared__ float red[4];
  int lane = threadIdx.x & 63, w = threadIdx.x >> 6;
  if (lane == 0) red[w] = a;
  __syncthreads();
  if (threadIdx.x == 0) out[0] = (red[0]+red[1]+red[2]+red[3]) / (float)N + decb[0];
}

// ---------------- launch ----------------
extern "C" void kernel_launch(void* const* d_in, const int* in_sizes, int n_in,
                              void* d_out, int out_size, void* d_ws, size_t ws_size,
                              hipStream_t stream)
{
  const float* nf   = (const float*)d_in[0];
  const int*   src  = (const int*)  d_in[1];
  const int*   dst  = (const int*)  d_in[2];
  const float* encW = (const float*)d_in[3];
  const float* encb = (const float*)d_in[4];
  const float* Wq   = (const float*)d_in[5];
  const float* Wk   = (const float*)d_in[6];
  const float* Wv   = (const float*)d_in[7];
  const float* Wo   = (const float*)d_in[8];
  const float* ln1g = (const float*)d_in[9];
  const float* ln1b = (const float*)d_in[10];
  const float* W1   = (const float*)d_in[11];
  const float* b1   = (const float*)d_in[12];
  const float* W2   = (const float*)d_in[13];
  const float* b2   = (const float*)d_in[14];
  const float* ln2g = (const float*)d_in[15];
  const float* ln2b = (const float*)d_in[16];
  const float* decW = (const float*)d_in[17];
  const float* decb = (const float*)d_in[18];
  float* out = (float*)d_out;

  const int N = in_sizes[0] / 16;
  const int E = in_sizes[1];
  const int NB = (N + 1023) / 1024;

  float* ws   = (float*)d_ws;
  float* h    = ws;                              // [N,128] f32
  float* h1   = h  + (size_t)N*128;              // [N,128] f32
  float* q    = h1 + (size_t)N*128;              // [N,128] f32
  u16*  hb    = (u16*)(q + (size_t)N*128);       // [N,128] bf16
  u16*  h1b   = hb  + (size_t)N*128;             // [N,128] bf16
  u16*  kvb   = h1b + (size_t)N*128;             // [N,256] bf16 (k | v)
  u16*  savb  = kvb + (size_t)N*256;             // [N,128] bf16 (attn out)
  u16*  fbb   = savb + (size_t)N*128;            // [N,512] bf16 (ffn hidden)
  int* deg    = (int*)(fbb + (size_t)N*512);
  int* offs   = deg + N;
  int* cursor = offs + N + 1;
  int* csr    = cursor + N;                      // holds src-node ids
  int* bsum   = csr + E;
  float* partials = (float*)(bsum + ((NB + 255) & ~255));
  u16* wbuf   = (u16*)(partials + 512);          // bf16 weights
  u16* wqkv   = wbuf;                            // [3][384][128]
  u16* wo_b   = wbuf + 147456;                   // [3][128][128]
  u16* w1_b   = wbuf + 196608;                   // [3][512][128]
  u16* w2_b   = wbuf + 393216;                   // [3][128][512]

  hipMemsetAsync(deg, 0, sizeof(int)*N, stream);
  count_kernel<<<(E+255)/256, 256, 0, stream>>>(dst, deg, E);
  scan_bsum<<<NB, 256, 0, stream>>>(deg, bsum, N);
  scan_bbase<<<1, 64, 0, stream>>>(bsum, NB);
  scan_write<<<NB, 256, 0, stream>>>(deg, bsum, offs, cursor, N);
  fill_kernel<<<(E+255)/256, 256, 0, stream>>>(dst, src, cursor, csr, E);

  convert_weights<<<(589824+255)/256, 256, 0, stream>>>(Wq, Wk, Wv, Wo, W1, W2, wbuf);

  encoder_kernel<<<(N+1)/2, 256, 0, stream>>>(nf, encW, encb, h, hb, N);

  const int gmx = (N + 127)/128;
  for (int l = 0; l < LAYERS; l++) {
    const u16* wqkv_l = wqkv + (size_t)l*384*128;
    const u16* wo_l   = wo_b + (size_t)l*128*128;
    const u16* w1_l   = w1_b + (size_t)l*512*128;
    const u16* w2_l   = w2_b + (size_t)l*128*512;

    gemm_qkv<<<dim3(gmx,3), 256, 0, stream>>>(hb, wqkv_l, q, kvb, N);

    attn_kernel<<<(N+15)/16, 256, 0, stream>>>(q, kvb, offs, csr, savb, N);

    gemm_ln<128><<<dim3(gmx,1), 256, 0, stream>>>(
        savb, wo_l, nullptr, h, ln1g + l*D, ln1b + l*D, h1, h1b, N);

    gemm_relu<<<dim3(gmx,4), 256, 0, stream>>>(h1b, w1_l, b1 + l*DFF, fbb, N);

    gemm_ln<512><<<dim3(gmx,1), 256, 0, stream>>>(
        fbb, w2_l, b2 + l*D, h1, ln2g + l*D, ln2b + l*D, h, hb, N);
  }

  dec_partial<<<256, 256, 0, stream>>>(h, decW, partials, N);
  dec_final<<<1, 256, 0, stream>>>(partials, decb, out, N);
}

// Round 5
// 567.563 us; speedup vs baseline: 4.0668x; 1.2650x over previous
//
#include <hip/hip_runtime.h>
#include <math.h>

static constexpr int D   = 128;
static constexpr int DFF = 512;
static constexpr int LAYERS = 3;
static constexpr float CLAMP_V = 5.0f;
static constexpr float LN_EPS = 1e-5f;

typedef unsigned short u16;
typedef unsigned int   u32;
typedef short bf16x8 __attribute__((ext_vector_type(8)));
typedef float f32x4  __attribute__((ext_vector_type(4)));

__device__ inline float4 ld4(const float* p){ return *reinterpret_cast<const float4*>(p); }
__device__ inline u16 f2bf(float f){ u32 u = __float_as_uint(f); return (u16)((u + 0x7fff + ((u>>16)&1)) >> 16); }
__device__ inline float bl(u32 u){ return __uint_as_float(u << 16); }
__device__ inline float bh(u32 u){ return __uint_as_float(u & 0xffff0000u); }

__device__ inline void gload_lds16(const void* g, void* l) {
  __builtin_amdgcn_global_load_lds(
      (const __attribute__((address_space(1))) void*)g,
      (__attribute__((address_space(3))) void*)l, 16, 0, 0);
}

// ---------------- CSR build ----------------
__global__ __launch_bounds__(256) void count_kernel(const int* __restrict__ dst,
                                                    int* __restrict__ deg, int E)
{
  int e = blockIdx.x*256 + threadIdx.x;
  if (e < E) atomicAdd(&deg[dst[e]], 1);
}

__global__ __launch_bounds__(256) void scan_bsum(const int* __restrict__ deg,
                                                 int* __restrict__ bsum, int N)
{
  const int i0 = blockIdx.x*1024 + threadIdx.x*4;
  int s = 0;
  if (i0 + 3 < N) { int4 v = *(const int4*)&deg[i0]; s = v.x+v.y+v.z+v.w; }
  else { for (int t = 0; t < 4; t++) if (i0+t < N) s += deg[i0+t]; }
  #pragma unroll
  for (int off = 1; off < 64; off <<= 1) s += __shfl_xor(s, off);
  __shared__ int ws_[4];
  if ((threadIdx.x & 63) == 0) ws_[threadIdx.x >> 6] = s;
  __syncthreads();
  if (threadIdx.x == 0) bsum[blockIdx.x] = ws_[0]+ws_[1]+ws_[2]+ws_[3];
}

__global__ __launch_bounds__(64) void scan_bbase(int* __restrict__ bsum, int NB)
{
  const int tid = threadIdx.x;
  int base = 0;
  for (int c = 0; c < NB; c += 64) {
    const int idx = c + tid;
    int v = (idx < NB) ? bsum[idx] : 0;
    const int orig = v;
    #pragma unroll
    for (int off = 1; off < 64; off <<= 1) {
      int t = __shfl_up(v, off);
      if (tid >= off) v += t;
    }
    if (idx < NB) bsum[idx] = base + v - orig;
    base += __shfl(v, 63);
  }
}

__global__ __launch_bounds__(256) void scan_write(const int* __restrict__ deg,
    const int* __restrict__ bbase, int* __restrict__ offs, int* __restrict__ cursor, int N)
{
  const int i0 = blockIdx.x*1024 + threadIdx.x*4;
  int v[4] = {0,0,0,0};
  if (i0 + 3 < N) { int4 t = *(const int4*)&deg[i0]; v[0]=t.x; v[1]=t.y; v[2]=t.z; v[3]=t.w; }
  else { for (int t = 0; t < 4; t++) if (i0+t < N) v[t] = deg[i0+t]; }
  const int s = v[0]+v[1]+v[2]+v[3];
  const int lane = threadIdx.x & 63, w = threadIdx.x >> 6;
  int inc = s;
  #pragma unroll
  for (int off = 1; off < 64; off <<= 1) {
    int t = __shfl_up(inc, off);
    if (lane >= off) inc += t;
  }
  __shared__ int wsum[4];
  if (lane == 63) wsum[w] = inc;
  __syncthreads();
  int wb = 0;
  for (int t = 0; t < 4; t++) if (t < w) wb += wsum[t];
  int run = bbase[blockIdx.x] + wb + inc - s;
  #pragma unroll
  for (int t = 0; t < 4; t++) {
    if (i0 + t < N) { offs[i0+t] = run; cursor[i0+t] = run; run += v[t]; }
  }
  if (i0 <= N-1 && N-1 < i0+4) offs[N] = run;
}

__global__ __launch_bounds__(256) void fill_kernel(const int* __restrict__ dst,
    const int* __restrict__ src, int* __restrict__ cursor, int* __restrict__ csr_src, int E)
{
  int e = blockIdx.x*256 + threadIdx.x;
  if (e < E) {
    int p = atomicAdd(&cursor[dst[e]], 1);
    csr_src[p] = src[e];
  }
}

// ---------------- weight conversion to bf16 ----------------
__global__ __launch_bounds__(256) void convert_weights(
    const float* __restrict__ Wq, const float* __restrict__ Wk, const float* __restrict__ Wv,
    const float* __restrict__ Wo, const float* __restrict__ W1, const float* __restrict__ W2,
    u16* __restrict__ out)
{
  const int SQKV = 3*384*128;
  const int SWO  = 3*128*128;
  const int SW1  = 3*512*128;
  const int SW2  = 3*128*512;
  int i = blockIdx.x*256 + threadIdx.x;
  if (i >= SQKV+SWO+SW1+SW2) return;
  float v;
  if (i < SQKV) {
    int l = i / (384*128), rem = i % (384*128);
    int row = rem / 128, col = rem % 128;
    const float* W = (row < 128) ? Wq : ((row < 256) ? Wk : Wv);
    v = W[(size_t)l*128*128 + (size_t)(row & 127)*128 + col];
  } else if (i < SQKV+SWO) {
    v = Wo[i - SQKV];
  } else if (i < SQKV+SWO+SW1) {
    v = W1[i - SQKV - SWO];
  } else {
    v = W2[i - SQKV - SWO - SW1];
  }
  out[i] = f2bf(v);
}

// ---------------- encoder (f32 + bf16 dual write) ----------------
__global__ __launch_bounds__(256) void encoder_kernel(
    const float* __restrict__ nf, const float* __restrict__ W,
    const float* __restrict__ b, float* __restrict__ h, u16* __restrict__ hb, int N)
{
  int n = blockIdx.x*2 + (threadIdx.x >> 7);
  int d = threadIdx.x & 127;
  if (n >= N) return;
  const float* nr = nf + (size_t)n*16;
  const float* wr = W  + (size_t)d*16;
  float s = b[d];
  #pragma unroll
  for (int kk = 0; kk < 16; kk++) s = fmaf(nr[kk], wr[kk], s);
  h[(size_t)n*D + d]  = s;
  hb[(size_t)n*D + d] = f2bf(s);
}

// ---------------- shared MFMA GEMM core: 128x128 tile (QKV) ----------------
template<int K>
__device__ inline void gemm_core(const u16* __restrict__ A, const u16* __restrict__ B,
                                 int M, int m0, u16* lA, u16* lB, f32x4 acc[4][4])
{
  const int tid  = threadIdx.x;
  const int lane = tid & 63;
  const int wid  = tid >> 6;
  const int wr   = wid >> 1, wc = wid & 1;

  const int ldrow = lane >> 3;
  const int gran  = (lane & 7) ^ ldrow;

  #pragma unroll
  for (int ks = 0; ks < K/64; ks++) {
    __syncthreads();
    const int k0 = ks*64 + gran*8;
    #pragma unroll
    for (int is = 0; is < 4; is++) {
      const int r  = wid*32 + is*8;
      int gm = m0 + r + ldrow; if (gm >= M) gm = M - 1;
      gload_lds16(A + (size_t)gm*K + k0, &lA[r*64]);
      gload_lds16(B + (size_t)(r + ldrow)*K + k0, &lB[r*64]);
    }
    asm volatile("s_waitcnt vmcnt(0)" ::: "memory");
    __syncthreads();

    #pragma unroll
    for (int k2 = 0; k2 < 2; k2++) {
      bf16x8 af[4], bfr[4];
      const int kq = k2*4 + (lane >> 4);
      #pragma unroll
      for (int mi = 0; mi < 4; mi++) {
        const int r = wr*64 + mi*16 + (lane & 15);
        af[mi] = *(const bf16x8*)&lA[r*64 + ((kq ^ (r & 7)) << 3)];
      }
      #pragma unroll
      for (int ni = 0; ni < 4; ni++) {
        const int r = wc*64 + ni*16 + (lane & 15);
        bfr[ni] = *(const bf16x8*)&lB[r*64 + ((kq ^ (r & 7)) << 3)];
      }
      #pragma unroll
      for (int mi = 0; mi < 4; mi++)
        #pragma unroll
        for (int ni = 0; ni < 4; ni++)
          acc[mi][ni] = __builtin_amdgcn_mfma_f32_16x16x32_bf16(af[mi], bfr[ni], acc[mi][ni], 0, 0, 0);
    }
  }
}

// ---------------- QKV GEMM: y=0 -> q (f32), y=1,2 -> kvb (bf16, ldc 256) ----------------
__global__ __launch_bounds__(256) void gemm_qkv(
    const u16* __restrict__ A, const u16* __restrict__ B,
    float* __restrict__ qf, u16* __restrict__ kvb, int M)
{
  __shared__ u16 lA[128*64];
  __shared__ u16 lB[128*64];
  const int s  = blockIdx.y;
  const int m0 = blockIdx.x * 128;
  f32x4 acc[4][4];
  #pragma unroll
  for (int i = 0; i < 4; i++)
    #pragma unroll
    for (int j = 0; j < 4; j++) { acc[i][j][0]=0.f; acc[i][j][1]=0.f; acc[i][j][2]=0.f; acc[i][j][3]=0.f; }

  gemm_core<128>(A, B + (size_t)s*128*128, M, m0, lA, lB, acc);

  const int lane  = threadIdx.x & 63;
  const int wid   = threadIdx.x >> 6;
  const int wr    = wid >> 1, wc = wid & 1;
  const int rbase = m0 + wr*64 + ((lane >> 4) << 2);
  const int cbase = wc*64 + (lane & 15);
  #pragma unroll
  for (int ni = 0; ni < 4; ni++) {
    const int col = cbase + ni*16;
    #pragma unroll
    for (int mi = 0; mi < 4; mi++) {
      #pragma unroll
      for (int r = 0; r < 4; r++) {
        const int gm = rbase + mi*16 + r;
        if (gm < M) {
          if (s == 0) qf[(size_t)gm*128 + col] = acc[mi][ni][r];
          else        kvb[(size_t)gm*256 + (s-1)*128 + col] = f2bf(acc[mi][ni][r]);
        }
      }
    }
  }
}

// ---------------- fused per-layer tail: Wo+LN1 -> FFN1 -> FFN2+LN2 ----------------
// 64-row slab per block; h1 kept in registers (f32) + LDS (bf16, swizzled);
// FFN computed in 4 DFF-chunks of 128; W1/W2 chunks streamed into lB.
__global__ __launch_bounds__(256) void ffn_fused(
    const u16* __restrict__ savb, const u16* __restrict__ Wo,
    const u16* __restrict__ W1,   const u16* __restrict__ W2,
    const float* __restrict__ ln1g, const float* __restrict__ ln1b,
    const float* __restrict__ b1,   const float* __restrict__ b2,
    const float* __restrict__ ln2g, const float* __restrict__ ln2b,
    float* __restrict__ hf, u16* __restrict__ hb, int M)
{
  __shared__ u16 lA[64*64];      // 8 KB  (savb slab staging)
  __shared__ u16 lB[128*64];     // 16 KB (weight staging)
  __shared__ u16 h1s[64*128];    // 16 KB (h1 bf16, swizzled)
  __shared__ u16 fs[64*128];     // 16 KB (relu chunk bf16, swizzled)
  __shared__ float lsum[64][2];
  __shared__ float lsq[64][2];

  const int tid  = threadIdx.x;
  const int lane = tid & 63;
  const int wid  = tid >> 6;
  const int wr   = wid >> 1, wc = wid & 1;
  const int m0   = blockIdx.x * 64;

  const int ldrow = lane >> 3;
  const int gran  = (lane & 7) ^ ldrow;

  const int rbase_l = wr*32 + ((lane >> 4) << 2);  // local row base (+mi*16+r)
  const int cbase   = wc*64 + (lane & 15);         // col base (+ni*16)

  // ================= Phase 1: uh = savb @ Wo^T =================
  f32x4 acc1[2][4];
  #pragma unroll
  for (int i = 0; i < 2; i++)
    #pragma unroll
    for (int j = 0; j < 4; j++) { acc1[i][j][0]=0.f; acc1[i][j][1]=0.f; acc1[i][j][2]=0.f; acc1[i][j][3]=0.f; }

  #pragma unroll
  for (int ks = 0; ks < 2; ks++) {
    __syncthreads();
    const int k0 = ks*64 + gran*8;
    #pragma unroll
    for (int is = 0; is < 2; is++) {
      const int r = wid*16 + is*8;
      int gm = m0 + r + ldrow; if (gm >= M) gm = M - 1;
      gload_lds16(savb + (size_t)gm*128 + k0, &lA[r*64]);
    }
    #pragma unroll
    for (int is = 0; is < 4; is++) {
      const int r = wid*32 + is*8;
      gload_lds16(Wo + (size_t)(r + ldrow)*128 + k0, &lB[r*64]);
    }
    asm volatile("s_waitcnt vmcnt(0)" ::: "memory");
    __syncthreads();
    #pragma unroll
    for (int k2 = 0; k2 < 2; k2++) {
      const int kq = k2*4 + (lane >> 4);
      bf16x8 af[2], bfr[4];
      #pragma unroll
      for (int mi = 0; mi < 2; mi++) {
        const int r = wr*32 + mi*16 + (lane & 15);
        af[mi] = *(const bf16x8*)&lA[r*64 + ((kq ^ (r & 7)) << 3)];
      }
      #pragma unroll
      for (int ni = 0; ni < 4; ni++) {
        const int r = wc*64 + ni*16 + (lane & 15);
        bfr[ni] = *(const bf16x8*)&lB[r*64 + ((kq ^ (r & 7)) << 3)];
      }
      #pragma unroll
      for (int mi = 0; mi < 2; mi++)
        #pragma unroll
        for (int ni = 0; ni < 4; ni++)
          acc1[mi][ni] = __builtin_amdgcn_mfma_f32_16x16x32_bf16(af[mi], bfr[ni], acc1[mi][ni], 0, 0, 0);
    }
  }

  // Phase 1 epilogue: x = uh + h_res; LN1 -> acc1 (h1 f32) + h1s (bf16)
  #pragma unroll
  for (int mi = 0; mi < 2; mi++) {
    #pragma unroll
    for (int r = 0; r < 4; r++) {
      const int lrow = rbase_l + mi*16 + r;
      int gr = m0 + lrow; if (gr >= M) gr = M - 1;
      float ps = 0.f, pq = 0.f;
      #pragma unroll
      for (int ni = 0; ni < 4; ni++) {
        const int col = cbase + ni*16;
        float x = acc1[mi][ni][r] + hf[(size_t)gr*128 + col];
        acc1[mi][ni][r] = x;
        ps += x; pq += x*x;
      }
      #pragma unroll
      for (int off = 1; off < 16; off <<= 1) { ps += __shfl_xor(ps, off); pq += __shfl_xor(pq, off); }
      if ((lane & 15) == 0) { lsum[lrow][wc] = ps; lsq[lrow][wc] = pq; }
    }
  }
  __syncthreads();
  #pragma unroll
  for (int mi = 0; mi < 2; mi++) {
    #pragma unroll
    for (int r = 0; r < 4; r++) {
      const int lrow = rbase_l + mi*16 + r;
      const float mean = (lsum[lrow][0] + lsum[lrow][1]) * (1.0f/128.0f);
      float var = (lsq[lrow][0] + lsq[lrow][1]) * (1.0f/128.0f) - mean*mean;
      const float rstd = rsqrtf(fmaxf(var, 0.f) + LN_EPS);
      #pragma unroll
      for (int ni = 0; ni < 4; ni++) {
        const int col = cbase + ni*16;
        float o = (acc1[mi][ni][r] - mean) * rstd * ln1g[col] + ln1b[col];
        acc1[mi][ni][r] = o;             // keep h1 (f32) in regs
        const int g16 = col >> 3;
        const int slot = ((g16 & 7) ^ (lrow & 7)) | (g16 & 8);
        h1s[lrow*128 + slot*8 + (col & 7)] = f2bf(o);
      }
    }
  }

  // ================= Phase 2+3: FFN over 4 chunks of 128 =================
  f32x4 acc3[2][4];
  #pragma unroll
  for (int i = 0; i < 2; i++)
    #pragma unroll
    for (int j = 0; j < 4; j++) { acc3[i][j][0]=0.f; acc3[i][j][1]=0.f; acc3[i][j][2]=0.f; acc3[i][j][3]=0.f; }

  for (int c = 0; c < 4; c++) {
    // ---- f_c = relu(h1 @ W1c^T + b1c) ----
    f32x4 acc2[2][4];
    #pragma unroll
    for (int i = 0; i < 2; i++)
      #pragma unroll
      for (int j = 0; j < 4; j++) { acc2[i][j][0]=0.f; acc2[i][j][1]=0.f; acc2[i][j][2]=0.f; acc2[i][j][3]=0.f; }

    #pragma unroll
    for (int s = 0; s < 2; s++) {
      __syncthreads();
      const int k0 = s*64 + gran*8;
      #pragma unroll
      for (int is = 0; is < 4; is++) {
        const int r = wid*32 + is*8;
        gload_lds16(W1 + (size_t)(c*128 + r + ldrow)*128 + k0, &lB[r*64]);
      }
      asm volatile("s_waitcnt vmcnt(0)" ::: "memory");
      __syncthreads();
      #pragma unroll
      for (int k2 = 0; k2 < 2; k2++) {
        const int kql = k2*4 + (lane >> 4);
        const int kqa = s*8 + kql;
        bf16x8 af[2], bfr[4];
        #pragma unroll
        for (int mi = 0; mi < 2; mi++) {
          const int r = wr*32 + mi*16 + (lane & 15);
          const int slot = ((kqa & 7) ^ (r & 7)) | (kqa & 8);
          af[mi] = *(const bf16x8*)&h1s[r*128 + slot*8];
        }
        #pragma unroll
        for (int ni = 0; ni < 4; ni++) {
          const int r = wc*64 + ni*16 + (lane & 15);
          bfr[ni] = *(const bf16x8*)&lB[r*64 + ((kql ^ (r & 7)) << 3)];
        }
        #pragma unroll
        for (int mi = 0; mi < 2; mi++)
          #pragma unroll
          for (int ni = 0; ni < 4; ni++)
            acc2[mi][ni] = __builtin_amdgcn_mfma_f32_16x16x32_bf16(af[mi], bfr[ni], acc2[mi][ni], 0, 0, 0);
      }
    }
    __syncthreads();   // prior fs readers (chunk c-1) are done; safe to overwrite
    #pragma unroll
    for (int mi = 0; mi < 2; mi++) {
      #pragma unroll
      for (int r = 0; r < 4; r++) {
        const int lrow = rbase_l + mi*16 + r;
        #pragma unroll
        for (int ni = 0; ni < 4; ni++) {
          const int col = cbase + ni*16;
          float v = fmaxf(acc2[mi][ni][r] + b1[c*128 + col], 0.f);
          const int g16 = col >> 3;
          const int slot = ((g16 & 7) ^ (lrow & 7)) | (g16 & 8);
          fs[lrow*128 + slot*8 + (col & 7)] = f2bf(v);
        }
      }
    }

    // ---- acc3 += f_c @ W2c^T ----
    #pragma unroll
    for (int s = 0; s < 2; s++) {
      __syncthreads();
      const int k0 = s*64 + gran*8;
      #pragma unroll
      for (int is = 0; is < 4; is++) {
        const int r = wid*32 + is*8;
        gload_lds16(W2 + (size_t)(r + ldrow)*512 + c*128 + k0, &lB[r*64]);
      }
      asm volatile("s_waitcnt vmcnt(0)" ::: "memory");
      __syncthreads();
      #pragma unroll
      for (int k2 = 0; k2 < 2; k2++) {
        const int kql = k2*4 + (lane >> 4);
        const int kqa = s*8 + kql;
        bf16x8 af[2], bfr[4];
        #pragma unroll
        for (int mi = 0; mi < 2; mi++) {
          const int r = wr*32 + mi*16 + (lane & 15);
          const int slot = ((kqa & 7) ^ (r & 7)) | (kqa & 8);
          af[mi] = *(const bf16x8*)&fs[r*128 + slot*8];
        }
        #pragma unroll
        for (int ni = 0; ni < 4; ni++) {
          const int r = wc*64 + ni*16 + (lane & 15);
          bfr[ni] = *(const bf16x8*)&lB[r*64 + ((kql ^ (r & 7)) << 3)];
        }
        #pragma unroll
        for (int mi = 0; mi < 2; mi++)
          #pragma unroll
          for (int ni = 0; ni < 4; ni++)
            acc3[mi][ni] = __builtin_amdgcn_mfma_f32_16x16x32_bf16(af[mi], bfr[ni], acc3[mi][ni], 0, 0, 0);
      }
    }
  }

  // ================= Phase 4: h = LN2(h1 + ffn2 + b2) =================
  #pragma unroll
  for (int mi = 0; mi < 2; mi++) {
    #pragma unroll
    for (int r = 0; r < 4; r++) {
      const int lrow = rbase_l + mi*16 + r;
      float ps = 0.f, pq = 0.f;
      #pragma unroll
      for (int ni = 0; ni < 4; ni++) {
        const int col = cbase + ni*16;
        float x = acc3[mi][ni][r] + b2[col] + acc1[mi][ni][r];
        acc3[mi][ni][r] = x;
        ps += x; pq += x*x;
      }
      #pragma unroll
      for (int off = 1; off < 16; off <<= 1) { ps += __shfl_xor(ps, off); pq += __shfl_xor(pq, off); }
      if ((lane & 15) == 0) { lsum[lrow][wc] = ps; lsq[lrow][wc] = pq; }
    }
  }
  __syncthreads();
  #pragma unroll
  for (int mi = 0; mi < 2; mi++) {
    #pragma unroll
    for (int r = 0; r < 4; r++) {
      const int lrow = rbase_l + mi*16 + r;
      const int grow = m0 + lrow;
      if (grow >= M) continue;
      const float mean = (lsum[lrow][0] + lsum[lrow][1]) * (1.0f/128.0f);
      float var = (lsq[lrow][0] + lsq[lrow][1]) * (1.0f/128.0f) - mean*mean;
      const float rstd = rsqrtf(fmaxf(var, 0.f) + LN_EPS);
      #pragma unroll
      for (int ni = 0; ni < 4; ni++) {
        const int col = cbase + ni*16;
        float o = (acc3[mi][ni][r] - mean) * rstd * ln2g[col] + ln2b[col];
        hf[(size_t)grow*128 + col] = o;
        hb[(size_t)grow*128 + col] = f2bf(o);
      }
    }
  }
}

// ---------------- attention: single-pass, constant-shift softmax ----------------
__global__ __launch_bounds__(256) void attn_kernel(
    const float* __restrict__ q, const u16* __restrict__ kv,
    const int* __restrict__ offs, const int* __restrict__ csr_src,
    u16* __restrict__ outb, int N)
{
  const int tid = threadIdx.x;
  const int j   = tid & 15;
  const int n   = blockIdx.x*16 + (tid >> 4);
  if (n >= N) return;

  float qreg[8];
  *(float4*)&qreg[0] = ld4(&q[(size_t)n*128 + j*8]);
  *(float4*)&qreg[4] = ld4(&q[(size_t)n*128 + j*8 + 4]);

  const int start = offs[n];
  const int deg   = offs[n+1] - start;

  float s = 0.f;
  float acc[8] = {0,0,0,0,0,0,0,0};
  const int gb = tid & 48;

  for (int base = 0; base < deg; base += 16) {
    const int myidx = base + j;
    const int sn_mine = (myidx < deg) ? csr_src[start + myidx] : 0;
    const int cnt = (deg - base < 16) ? (deg - base) : 16;

    for (int b2 = 0; b2 < cnt; b2 += 4) {
      const int m4 = cnt - b2;
      uint4 K4[4], V4[4];
      #pragma unroll
      for (int u = 0; u < 4; u++) {
        const int sel = b2 + ((u < m4) ? u : 0);
        const int sn = __shfl(sn_mine, gb + sel);
        const u16* row = kv + (size_t)sn*256 + j*8;
        K4[u] = *(const uint4*)row;
        V4[u] = *(const uint4*)(row + 128);
      }
      #pragma unroll
      for (int u = 0; u < 4; u++) {
        if (u < m4) {
          float d = bl(K4[u].x)*qreg[0] + bh(K4[u].x)*qreg[1]
                  + bl(K4[u].y)*qreg[2] + bh(K4[u].y)*qreg[3]
                  + bl(K4[u].z)*qreg[4] + bh(K4[u].z)*qreg[5]
                  + bl(K4[u].w)*qreg[6] + bh(K4[u].w)*qreg[7];
          d += __shfl_xor(d, 1);
          float uu = fminf(fmaxf(d * 0.25f, -CLAMP_V), CLAMP_V);
          float e = __expf(uu - CLAMP_V);
          s += e;
          acc[0] = fmaf(e, bl(V4[u].x), acc[0]);
          acc[1] = fmaf(e, bh(V4[u].x), acc[1]);
          acc[2] = fmaf(e, bl(V4[u].y), acc[2]);
          acc[3] = fmaf(e, bh(V4[u].y), acc[3]);
          acc[4] = fmaf(e, bl(V4[u].z), acc[4]);
          acc[5] = fmaf(e, bh(V4[u].z), acc[5]);
          acc[6] = fmaf(e, bl(V4[u].w), acc[6]);
          acc[7] = fmaf(e, bh(V4[u].w), acc[7]);
        }
      }
    }
  }

  const float rs = (deg > 0) ? (1.0f / s) : 0.f;
  u16 o[8];
  #pragma unroll
  for (int t = 0; t < 8; t++) o[t] = f2bf(acc[t] * rs);
  *(uint4*)&outb[(size_t)n*128 + j*8] = *(const uint4*)o;
}

// ---------------- decoder + mean ----------------
__global__ __launch_bounds__(256) void dec_partial(const float* __restrict__ h,
    const float* __restrict__ W, float* __restrict__ partials, int N)
{
  float acc = 0.f;
  for (int n = blockIdx.x*256 + threadIdx.x; n < N; n += 256*256) {
    const float* hr = h + (size_t)n*D;
    float s = 0.f;
    #pragma unroll
    for (int t = 0; t < 32; t++) {
      float4 hv = ld4(&hr[t*4]); float4 wv = ld4(&W[t*4]);
      s += hv.x*wv.x + hv.y*wv.y + hv.z*wv.z + hv.w*wv.w;
    }
    acc += s;
  }
  #pragma unroll
  for (int off = 1; off < 64; off <<= 1) acc += __shfl_xor(acc, off);
  __shared__ float red[4];
  int lane = threadIdx.x & 63, w = threadIdx.x >> 6;
  if (lane == 0) red[w] = acc;
  __syncthreads();
  if (threadIdx.x == 0) partials[blockIdx.x] = red[0]+red[1]+red[2]+red[3];
}

__global__ __launch_bounds__(256) void dec_final(const float* __restrict__ partials,
    const float* __restrict__ decb, float* __restrict__ out, int N)
{
  float a = partials[threadIdx.x];
  #pragma unroll
  for (int off = 1; off < 64; off <<= 1) a += __shfl_xor(a, off);
  __shared__ float red[4];
  int lane = threadIdx.x & 63, w = threadIdx.x >> 6;
  if (lane == 0) red[w] = a;
  __syncthreads();
  if (threadIdx.x == 0) out[0] = (red[0]+red[1]+red[2]+red[3]) / (float)N + decb[0];
}

// ---------------- launch ----------------
extern "C" void kernel_launch(void* const* d_in, const int* in_sizes, int n_in,
                              void* d_out, int out_size, void* d_ws, size_t ws_size,
                              hipStream_t stream)
{
  const float* nf   = (const float*)d_in[0];
  const int*   src  = (const int*)  d_in[1];
  const int*   dst  = (const int*)  d_in[2];
  const float* encW = (const float*)d_in[3];
  const float* encb = (const float*)d_in[4];
  const float* Wq   = (const float*)d_in[5];
  const float* Wk   = (const float*)d_in[6];
  const float* Wv   = (const float*)d_in[7];
  const float* Wo   = (const float*)d_in[8];
  const float* ln1g = (const float*)d_in[9];
  const float* ln1b = (const float*)d_in[10];
  const float* W1   = (const float*)d_in[11];
  const float* b1   = (const float*)d_in[12];
  const float* W2   = (const float*)d_in[13];
  const float* b2   = (const float*)d_in[14];
  const float* ln2g = (const float*)d_in[15];
  const float* ln2b = (const float*)d_in[16];
  const float* decW = (const float*)d_in[17];
  const float* decb = (const float*)d_in[18];
  float* out = (float*)d_out;

  const int N = in_sizes[0] / 16;
  const int E = in_sizes[1];
  const int NB = (N + 1023) / 1024;

  float* ws   = (float*)d_ws;
  float* h    = ws;                              // [N,128] f32
  float* q    = h  + (size_t)N*128;              // [N,128] f32
  u16*  hb    = (u16*)(q + (size_t)N*128);       // [N,128] bf16
  u16*  kvb   = hb  + (size_t)N*128;             // [N,256] bf16 (k | v)
  u16*  savb  = kvb + (size_t)N*256;             // [N,128] bf16 (attn out)
  int* deg    = (int*)(savb + (size_t)N*128);
  int* offs   = deg + N;
  int* cursor = offs + N + 1;
  int* csr    = cursor + N;                      // holds src-node ids
  int* bsum   = csr + E;
  float* partials = (float*)(bsum + ((NB + 255) & ~255));
  u16* wbuf   = (u16*)(partials + 512);          // bf16 weights
  u16* wqkv   = wbuf;                            // [3][384][128]
  u16* wo_b   = wbuf + 147456;                   // [3][128][128]
  u16* w1_b   = wbuf + 196608;                   // [3][512][128]
  u16* w2_b   = wbuf + 393216;                   // [3][128][512]

  hipMemsetAsync(deg, 0, sizeof(int)*N, stream);
  count_kernel<<<(E+255)/256, 256, 0, stream>>>(dst, deg, E);
  scan_bsum<<<NB, 256, 0, stream>>>(deg, bsum, N);
  scan_bbase<<<1, 64, 0, stream>>>(bsum, NB);
  scan_write<<<NB, 256, 0, stream>>>(deg, bsum, offs, cursor, N);
  fill_kernel<<<(E+255)/256, 256, 0, stream>>>(dst, src, cursor, csr, E);

  convert_weights<<<(589824+255)/256, 256, 0, stream>>>(Wq, Wk, Wv, Wo, W1, W2, wbuf);

  encoder_kernel<<<(N+1)/2, 256, 0, stream>>>(nf, encW, encb, h, hb, N);

  const int gmx = (N + 127)/128;
  for (int l = 0; l < LAYERS; l++) {
    const u16* wqkv_l = wqkv + (size_t)l*384*128;
    const u16* wo_l   = wo_b + (size_t)l*128*128;
    const u16* w1_l   = w1_b + (size_t)l*512*128;
    const u16* w2_l   = w2_b + (size_t)l*128*512;

    gemm_qkv<<<dim3(gmx,3), 256, 0, stream>>>(hb, wqkv_l, q, kvb, N);

    attn_kernel<<<(N+15)/16, 256, 0, stream>>>(q, kvb, offs, csr, savb, N);

    ffn_fused<<<(N+63)/64, 256, 0, stream>>>(
        savb, wo_l, w1_l, w2_l,
        ln1g + l*D, ln1b + l*D, b1 + l*DFF, b2 + l*D, ln2g + l*D, ln2b + l*D,
        h, hb, N);
  }

  dec_partial<<<256, 256, 0, stream>>>(h, decW, partials, N);
  dec_final<<<1, 256, 0, stream>>>(partials, decb, out, N);
}

// Round 6
// 556.412 us; speedup vs baseline: 4.1483x; 1.0200x over previous
//
#include <hip/hip_runtime.h>
#include <math.h>

static constexpr int D   = 128;
static constexpr int DFF = 512;
static constexpr int LAYERS = 3;
static constexpr float CLAMP_V = 5.0f;
static constexpr float LN_EPS = 1e-5f;

typedef unsigned short u16;
typedef unsigned int   u32;
typedef short bf16x8 __attribute__((ext_vector_type(8)));
typedef float f32x4  __attribute__((ext_vector_type(4)));

__device__ inline float4 ld4(const float* p){ return *reinterpret_cast<const float4*>(p); }
__device__ inline u16 f2bf(float f){ u32 u = __float_as_uint(f); return (u16)((u + 0x7fff + ((u>>16)&1)) >> 16); }
__device__ inline float bl(u32 u){ return __uint_as_float(u << 16); }
__device__ inline float bh(u32 u){ return __uint_as_float(u & 0xffff0000u); }

__device__ inline void gload_lds16(const void* g, void* l) {
  __builtin_amdgcn_global_load_lds(
      (const __attribute__((address_space(1))) void*)g,
      (__attribute__((address_space(3))) void*)l, 16, 0, 0);
}

// ---------------- CSR build ----------------
__global__ __launch_bounds__(256) void count_kernel(const int* __restrict__ dst,
                                                    int* __restrict__ deg, int E)
{
  int e = blockIdx.x*256 + threadIdx.x;
  if (e < E) atomicAdd(&deg[dst[e]], 1);
}

__global__ __launch_bounds__(256) void scan_bsum(const int* __restrict__ deg,
                                                 int* __restrict__ bsum, int N)
{
  const int i0 = blockIdx.x*1024 + threadIdx.x*4;
  int s = 0;
  if (i0 + 3 < N) { int4 v = *(const int4*)&deg[i0]; s = v.x+v.y+v.z+v.w; }
  else { for (int t = 0; t < 4; t++) if (i0+t < N) s += deg[i0+t]; }
  #pragma unroll
  for (int off = 1; off < 64; off <<= 1) s += __shfl_xor(s, off);
  __shared__ int ws_[4];
  if ((threadIdx.x & 63) == 0) ws_[threadIdx.x >> 6] = s;
  __syncthreads();
  if (threadIdx.x == 0) bsum[blockIdx.x] = ws_[0]+ws_[1]+ws_[2]+ws_[3];
}

__global__ __launch_bounds__(64) void scan_bbase(int* __restrict__ bsum, int NB)
{
  const int tid = threadIdx.x;
  int base = 0;
  for (int c = 0; c < NB; c += 64) {
    const int idx = c + tid;
    int v = (idx < NB) ? bsum[idx] : 0;
    const int orig = v;
    #pragma unroll
    for (int off = 1; off < 64; off <<= 1) {
      int t = __shfl_up(v, off);
      if (tid >= off) v += t;
    }
    if (idx < NB) bsum[idx] = base + v - orig;
    base += __shfl(v, 63);
  }
}

__global__ __launch_bounds__(256) void scan_write(const int* __restrict__ deg,
    const int* __restrict__ bbase, int* __restrict__ offs, int* __restrict__ cursor, int N)
{
  const int i0 = blockIdx.x*1024 + threadIdx.x*4;
  int v[4] = {0,0,0,0};
  if (i0 + 3 < N) { int4 t = *(const int4*)&deg[i0]; v[0]=t.x; v[1]=t.y; v[2]=t.z; v[3]=t.w; }
  else { for (int t = 0; t < 4; t++) if (i0+t < N) v[t] = deg[i0+t]; }
  const int s = v[0]+v[1]+v[2]+v[3];
  const int lane = threadIdx.x & 63, w = threadIdx.x >> 6;
  int inc = s;
  #pragma unroll
  for (int off = 1; off < 64; off <<= 1) {
    int t = __shfl_up(inc, off);
    if (lane >= off) inc += t;
  }
  __shared__ int wsum[4];
  if (lane == 63) wsum[w] = inc;
  __syncthreads();
  int wb = 0;
  for (int t = 0; t < 4; t++) if (t < w) wb += wsum[t];
  int run = bbase[blockIdx.x] + wb + inc - s;
  #pragma unroll
  for (int t = 0; t < 4; t++) {
    if (i0 + t < N) { offs[i0+t] = run; cursor[i0+t] = run; run += v[t]; }
  }
  if (i0 <= N-1 && N-1 < i0+4) offs[N] = run;
}

__global__ __launch_bounds__(256) void fill_kernel(const int* __restrict__ dst,
    const int* __restrict__ src, int* __restrict__ cursor, int* __restrict__ csr_src, int E)
{
  int e = blockIdx.x*256 + threadIdx.x;
  if (e < E) {
    int p = atomicAdd(&cursor[dst[e]], 1);
    csr_src[p] = src[e];
  }
}

// ---------------- weight conversion to bf16 ----------------
__global__ __launch_bounds__(256) void convert_weights(
    const float* __restrict__ Wq, const float* __restrict__ Wk, const float* __restrict__ Wv,
    const float* __restrict__ Wo, const float* __restrict__ W1, const float* __restrict__ W2,
    u16* __restrict__ out)
{
  const int SQKV = 3*384*128;
  const int SWO  = 3*128*128;
  const int SW1  = 3*512*128;
  const int SW2  = 3*128*512;
  int i = blockIdx.x*256 + threadIdx.x;
  if (i >= SQKV+SWO+SW1+SW2) return;
  float v;
  if (i < SQKV) {
    int l = i / (384*128), rem = i % (384*128);
    int row = rem / 128, col = rem % 128;
    const float* W = (row < 128) ? Wq : ((row < 256) ? Wk : Wv);
    v = W[(size_t)l*128*128 + (size_t)(row & 127)*128 + col];
  } else if (i < SQKV+SWO) {
    v = Wo[i - SQKV];
  } else if (i < SQKV+SWO+SW1) {
    v = W1[i - SQKV - SWO];
  } else {
    v = W2[i - SQKV - SWO - SW1];
  }
  out[i] = f2bf(v);
}

// ---------------- encoder (f32 + bf16 dual write) ----------------
__global__ __launch_bounds__(256) void encoder_kernel(
    const float* __restrict__ nf, const float* __restrict__ W,
    const float* __restrict__ b, float* __restrict__ h, u16* __restrict__ hb, int N)
{
  int n = blockIdx.x*2 + (threadIdx.x >> 7);
  int d = threadIdx.x & 127;
  if (n >= N) return;
  const float* nr = nf + (size_t)n*16;
  const float* wr = W  + (size_t)d*16;
  float s = b[d];
  #pragma unroll
  for (int kk = 0; kk < 16; kk++) s = fmaf(nr[kk], wr[kk], s);
  h[(size_t)n*D + d]  = s;
  hb[(size_t)n*D + d] = f2bf(s);
}

// ---------------- MFMA helpers ----------------
// A tile [128][64] per-ks layout (64-col, slot swizzle), 4x4 acc
__device__ inline void mfma_step128(const u16* __restrict__ la, const u16* __restrict__ lb,
                                    int lane, int wr, int wc, f32x4 (&acc)[4][4])
{
  #pragma unroll
  for (int k2 = 0; k2 < 2; k2++) {
    bf16x8 af[4], bfr[4];
    const int kq = k2*4 + (lane >> 4);
    #pragma unroll
    for (int mi = 0; mi < 4; mi++) {
      const int r = wr*64 + mi*16 + (lane & 15);
      af[mi] = *(const bf16x8*)&la[r*64 + ((kq ^ (r & 7)) << 3)];
    }
    #pragma unroll
    for (int ni = 0; ni < 4; ni++) {
      const int r = wc*64 + ni*16 + (lane & 15);
      bfr[ni] = *(const bf16x8*)&lb[r*64 + ((kq ^ (r & 7)) << 3)];
    }
    #pragma unroll
    for (int mi = 0; mi < 4; mi++)
      #pragma unroll
      for (int ni = 0; ni < 4; ni++)
        acc[mi][ni] = __builtin_amdgcn_mfma_f32_16x16x32_bf16(af[mi], bfr[ni], acc[mi][ni], 0, 0, 0);
  }
}

// A tile [64][128] swizzled activation layout, B tile [128][64]; 2x4 acc
__device__ inline void mfma_stage64(const u16* __restrict__ Atile, const u16* __restrict__ Btile,
                                    int lane, int wr, int wc, int kabase, f32x4 (&acc)[2][4])
{
  #pragma unroll
  for (int k2 = 0; k2 < 2; k2++) {
    const int kql = k2*4 + (lane >> 4);
    const int kqa = kabase + kql;
    bf16x8 af[2], bfr[4];
    #pragma unroll
    for (int mi = 0; mi < 2; mi++) {
      const int r = wr*32 + mi*16 + (lane & 15);
      const int slot = ((kqa & 7) ^ (r & 7)) | (kqa & 8);
      af[mi] = *(const bf16x8*)&Atile[r*128 + slot*8];
    }
    #pragma unroll
    for (int ni = 0; ni < 4; ni++) {
      const int r = wc*64 + ni*16 + (lane & 15);
      bfr[ni] = *(const bf16x8*)&Btile[r*64 + ((kql ^ (r & 7)) << 3)];
    }
    #pragma unroll
    for (int mi = 0; mi < 2; mi++)
      #pragma unroll
      for (int ni = 0; ni < 4; ni++)
        acc[mi][ni] = __builtin_amdgcn_mfma_f32_16x16x32_bf16(af[mi], bfr[ni], acc[mi][ni], 0, 0, 0);
  }
}

// ---------------- QKV GEMM (double-buffered): y=0 -> q f32, y=1,2 -> kvb bf16 ----------------
__global__ __launch_bounds__(256) void gemm_qkv(
    const u16* __restrict__ A, const u16* __restrict__ B,
    float* __restrict__ qf, u16* __restrict__ kvb, int M)
{
  __shared__ u16 lA[2][128*64];
  __shared__ u16 lB[2][128*64];
  const int sY = blockIdx.y;
  const int m0 = blockIdx.x * 128;
  const int tid = threadIdx.x, lane = tid & 63, wid = tid >> 6;
  const int wr = wid >> 1, wc = wid & 1;
  const int ldrow = lane >> 3;
  const int gran  = (lane & 7) ^ ldrow;
  const u16* Bm = B + (size_t)sY*128*128;

  f32x4 acc[4][4];
  #pragma unroll
  for (int i = 0; i < 4; i++)
    #pragma unroll
    for (int j = 0; j < 4; j++) { acc[i][j][0]=0.f; acc[i][j][1]=0.f; acc[i][j][2]=0.f; acc[i][j][3]=0.f; }

  auto issue = [&](int ks) {
    const int k0 = ks*64 + gran*8;
    #pragma unroll
    for (int is = 0; is < 4; is++) {
      const int r = wid*32 + is*8;
      int gm = m0 + r + ldrow; if (gm >= M) gm = M - 1;
      gload_lds16(A + (size_t)gm*128 + k0, &lA[ks][r*64]);
      gload_lds16(Bm + (size_t)(r + ldrow)*128 + k0, &lB[ks][r*64]);
    }
  };

  issue(0);
  asm volatile("s_waitcnt vmcnt(0)" ::: "memory");
  __syncthreads();
  issue(1);
  mfma_step128(lA[0], lB[0], lane, wr, wc, acc);
  asm volatile("s_waitcnt vmcnt(0)" ::: "memory");
  __syncthreads();
  mfma_step128(lA[1], lB[1], lane, wr, wc, acc);

  const int rbase = m0 + wr*64 + ((lane >> 4) << 2);
  const int cbase = wc*64 + (lane & 15);
  #pragma unroll
  for (int ni = 0; ni < 4; ni++) {
    const int col = cbase + ni*16;
    #pragma unroll
    for (int mi = 0; mi < 4; mi++) {
      #pragma unroll
      for (int r = 0; r < 4; r++) {
        const int gm = rbase + mi*16 + r;
        if (gm < M) {
          if (sY == 0) qf[(size_t)gm*128 + col] = acc[mi][ni][r];
          else         kvb[(size_t)gm*256 + (sY-1)*128 + col] = f2bf(acc[mi][ni][r]);
        }
      }
    }
  }
}

// ---------------- fused per-layer tail, 18-stage software pipeline ----------------
// stages: 0-1 Wo(ks0,ks1) -> acc1 ; per chunk c: W1c ks0/ks1 -> acc2, W2c ks0/ks1 -> acc3
__global__ __launch_bounds__(256) void ffn_fused(
    const u16* __restrict__ savb, const u16* __restrict__ Wo,
    const u16* __restrict__ W1,   const u16* __restrict__ W2,
    const float* __restrict__ ln1g, const float* __restrict__ ln1b,
    const float* __restrict__ b1,   const float* __restrict__ b2,
    const float* __restrict__ ln2g, const float* __restrict__ ln2b,
    float* __restrict__ hf, u16* __restrict__ hb, int M)
{
  __shared__ u16 lB[2][128*64];  // 32 KB weight double-buffer
  __shared__ u16 h1s[64*128];    // 16 KB h1 bf16 (swizzled)
  __shared__ u16 fs[64*128];     // 16 KB relu chunk; stages 0-1: savb A-slab (same layout)
  __shared__ float lsum[64][2];
  __shared__ float lsq[64][2];

  const int tid  = threadIdx.x;
  const int lane = tid & 63;
  const int wid  = tid >> 6;
  const int wr   = wid >> 1, wc = wid & 1;
  const int m0   = blockIdx.x * 64;

  const int ldrow = lane >> 3;
  const int gran  = (lane & 7) ^ ldrow;

  const int rbase_l = wr*32 + ((lane >> 4) << 2);
  const int cbase   = wc*64 + (lane & 15);

  auto stage_issue = [&](int s) {
    u16* dst = lB[s & 1];
    #pragma unroll
    for (int is = 0; is < 4; is++) {
      const int r = wid*32 + is*8;
      const u16* gp;
      if (s < 2) gp = Wo + (size_t)(r + ldrow)*128 + s*64;
      else {
        const int t = s - 2, c = t >> 2, k = t & 3;
        gp = (k < 2) ? (W1 + (size_t)(c*128 + r + ldrow)*128 + k*64)
                     : (W2 + (size_t)(r + ldrow)*512 + c*128 + (k-2)*64);
      }
      gload_lds16(gp + gran*8, dst + r*64);
    }
  };

  // prologue: savb slab into fs ([64][128] swizzled) + stage 0 weights
  #pragma unroll
  for (int is = 0; is < 4; is++) {
    const int r0 = wid*16 + is*4;           // 4 rows per issue
    const int rr = r0 + (lane >> 4);
    int gm = m0 + rr; if (gm >= M) gm = M - 1;
    const int gsrc = ((lane & 7) ^ (rr & 7)) | (lane & 8);
    gload_lds16(savb + (size_t)gm*128 + gsrc*8, &fs[r0*128]);
  }
  stage_issue(0);

  f32x4 acc1[2][4], acc2[2][4], acc3[2][4];
  #pragma unroll
  for (int i = 0; i < 2; i++)
    #pragma unroll
    for (int j = 0; j < 4; j++) {
      acc1[i][j][0]=0.f; acc1[i][j][1]=0.f; acc1[i][j][2]=0.f; acc1[i][j][3]=0.f;
      acc3[i][j][0]=0.f; acc3[i][j][1]=0.f; acc3[i][j][2]=0.f; acc3[i][j][3]=0.f;
    }

  asm volatile("s_waitcnt vmcnt(0)" ::: "memory");
  __syncthreads();

  #pragma unroll
  for (int s = 0; s < 18; s++) {
    if (s < 17) stage_issue(s + 1);

    if (s >= 2 && ((s - 2) & 3) == 0) {
      #pragma unroll
      for (int i = 0; i < 2; i++)
        #pragma unroll
        for (int j = 0; j < 4; j++) { acc2[i][j][0]=0.f; acc2[i][j][1]=0.f; acc2[i][j][2]=0.f; acc2[i][j][3]=0.f; }
    }

    if (s < 2)
      mfma_stage64(fs,  lB[s & 1], lane, wr, wc, (s & 1)*8, acc1);
    else if (((s - 2) & 3) < 2)
      mfma_stage64(h1s, lB[s & 1], lane, wr, wc, (s & 1)*8, acc2);
    else
      mfma_stage64(fs,  lB[s & 1], lane, wr, wc, (s & 1)*8, acc3);

    if (s == 1) {
      // LN1 epilogue: x = uh + h_res ; h1 -> acc1 (f32) + h1s (bf16 swizzled)
      #pragma unroll
      for (int mi = 0; mi < 2; mi++) {
        #pragma unroll
        for (int r = 0; r < 4; r++) {
          const int lrow = rbase_l + mi*16 + r;
          int gr = m0 + lrow; if (gr >= M) gr = M - 1;
          float ps = 0.f, pq = 0.f;
          #pragma unroll
          for (int ni = 0; ni < 4; ni++) {
            const int col = cbase + ni*16;
            float x = acc1[mi][ni][r] + hf[(size_t)gr*128 + col];
            acc1[mi][ni][r] = x;
            ps += x; pq += x*x;
          }
          #pragma unroll
          for (int off = 1; off < 16; off <<= 1) { ps += __shfl_xor(ps, off); pq += __shfl_xor(pq, off); }
          if ((lane & 15) == 0) { lsum[lrow][wc] = ps; lsq[lrow][wc] = pq; }
        }
      }
      __syncthreads();
      #pragma unroll
      for (int mi = 0; mi < 2; mi++) {
        #pragma unroll
        for (int r = 0; r < 4; r++) {
          const int lrow = rbase_l + mi*16 + r;
          const float mean = (lsum[lrow][0] + lsum[lrow][1]) * (1.0f/128.0f);
          float var = (lsq[lrow][0] + lsq[lrow][1]) * (1.0f/128.0f) - mean*mean;
          const float rstd = rsqrtf(fmaxf(var, 0.f) + LN_EPS);
          #pragma unroll
          for (int ni = 0; ni < 4; ni++) {
            const int col = cbase + ni*16;
            float o = (acc1[mi][ni][r] - mean) * rstd * ln1g[col] + ln1b[col];
            acc1[mi][ni][r] = o;
            const int g16 = col >> 3;
            const int slot = ((g16 & 7) ^ (lrow & 7)) | (g16 & 8);
            h1s[lrow*128 + slot*8 + (col & 7)] = f2bf(o);
          }
        }
      }
    } else if (s >= 2 && ((s - 2) & 3) == 1) {
      // relu epilogue for chunk c
      const int c = (s - 2) >> 2;
      #pragma unroll
      for (int mi = 0; mi < 2; mi++) {
        #pragma unroll
        for (int r = 0; r < 4; r++) {
          const int lrow = rbase_l + mi*16 + r;
          #pragma unroll
          for (int ni = 0; ni < 4; ni++) {
            const int col = cbase + ni*16;
            float v = fmaxf(acc2[mi][ni][r] + b1[c*128 + col], 0.f);
            const int g16 = col >> 3;
            const int slot = ((g16 & 7) ^ (lrow & 7)) | (g16 & 8);
            fs[lrow*128 + slot*8 + (col & 7)] = f2bf(v);
          }
        }
      }
    }

    if (s < 17) {
      asm volatile("s_waitcnt vmcnt(0)" ::: "memory");
      __syncthreads();
    }
  }

  // LN2 epilogue: h = LN2(h1 + ffn2 + b2)
  #pragma unroll
  for (int mi = 0; mi < 2; mi++) {
    #pragma unroll
    for (int r = 0; r < 4; r++) {
      const int lrow = rbase_l + mi*16 + r;
      float ps = 0.f, pq = 0.f;
      #pragma unroll
      for (int ni = 0; ni < 4; ni++) {
        const int col = cbase + ni*16;
        float x = acc3[mi][ni][r] + b2[col] + acc1[mi][ni][r];
        acc3[mi][ni][r] = x;
        ps += x; pq += x*x;
      }
      #pragma unroll
      for (int off = 1; off < 16; off <<= 1) { ps += __shfl_xor(ps, off); pq += __shfl_xor(pq, off); }
      if ((lane & 15) == 0) { lsum[lrow][wc] = ps; lsq[lrow][wc] = pq; }
    }
  }
  __syncthreads();
  #pragma unroll
  for (int mi = 0; mi < 2; mi++) {
    #pragma unroll
    for (int r = 0; r < 4; r++) {
      const int lrow = rbase_l + mi*16 + r;
      const int grow = m0 + lrow;
      if (grow >= M) continue;
      const float mean = (lsum[lrow][0] + lsum[lrow][1]) * (1.0f/128.0f);
      float var = (lsq[lrow][0] + lsq[lrow][1]) * (1.0f/128.0f) - mean*mean;
      const float rstd = rsqrtf(fmaxf(var, 0.f) + LN_EPS);
      #pragma unroll
      for (int ni = 0; ni < 4; ni++) {
        const int col = cbase + ni*16;
        float o = (acc3[mi][ni][r] - mean) * rstd * ln2g[col] + ln2b[col];
        hf[(size_t)grow*128 + col] = o;
        hb[(size_t)grow*128 + col] = f2bf(o);
      }
    }
  }
}

// ---------------- attention: single-pass, constant-shift softmax, 8-deep MLP ----------------
__global__ __launch_bounds__(256) void attn_kernel(
    const float* __restrict__ q, const u16* __restrict__ kv,
    const int* __restrict__ offs, const int* __restrict__ csr_src,
    u16* __restrict__ outb, int N)
{
  const int tid = threadIdx.x;
  const int j   = tid & 15;
  const int n   = blockIdx.x*16 + (tid >> 4);
  if (n >= N) return;

  float qreg[8];
  *(float4*)&qreg[0] = ld4(&q[(size_t)n*128 + j*8]);
  *(float4*)&qreg[4] = ld4(&q[(size_t)n*128 + j*8 + 4]);

  const int start = offs[n];
  const int deg   = offs[n+1] - start;

  float s = 0.f;
  float acc[8] = {0,0,0,0,0,0,0,0};
  const int gb = tid & 48;

  for (int base = 0; base < deg; base += 16) {
    const int myidx = base + j;
    const int sn_mine = (myidx < deg) ? csr_src[start + myidx] : 0;
    const int cnt = (deg - base < 16) ? (deg - base) : 16;

    for (int b2 = 0; b2 < cnt; b2 += 8) {
      const int m8 = cnt - b2;
      uint4 K4[8], V4[8];
      #pragma unroll
      for (int u = 0; u < 8; u++) {
        const int sel = b2 + ((u < m8) ? u : 0);
        const int sn = __shfl(sn_mine, gb + sel);
        const u16* row = kv + (size_t)sn*256 + j*8;
        K4[u] = *(const uint4*)row;
        V4[u] = *(const uint4*)(row + 128);
      }
      #pragma unroll
      for (int u = 0; u < 8; u++) {
        if (u < m8) {
          float d = bl(K4[u].x)*qreg[0] + bh(K4[u].x)*qreg[1]
                  + bl(K4[u].y)*qreg[2] + bh(K4[u].y)*qreg[3]
                  + bl(K4[u].z)*qreg[4] + bh(K4[u].z)*qreg[5]
                  + bl(K4[u].w)*qreg[6] + bh(K4[u].w)*qreg[7];
          d += __shfl_xor(d, 1);
          float uu = fminf(fmaxf(d * 0.25f, -CLAMP_V), CLAMP_V);
          float e = __expf(uu - CLAMP_V);
          s += e;
          acc[0] = fmaf(e, bl(V4[u].x), acc[0]);
          acc[1] = fmaf(e, bh(V4[u].x), acc[1]);
          acc[2] = fmaf(e, bl(V4[u].y), acc[2]);
          acc[3] = fmaf(e, bh(V4[u].y), acc[3]);
          acc[4] = fmaf(e, bl(V4[u].z), acc[4]);
          acc[5] = fmaf(e, bh(V4[u].z), acc[5]);
          acc[6] = fmaf(e, bl(V4[u].w), acc[6]);
          acc[7] = fmaf(e, bh(V4[u].w), acc[7]);
        }
      }
    }
  }

  const float rs = (deg > 0) ? (1.0f / s) : 0.f;
  u16 o[8];
  #pragma unroll
  for (int t = 0; t < 8; t++) o[t] = f2bf(acc[t] * rs);
  *(uint4*)&outb[(size_t)n*128 + j*8] = *(const uint4*)o;
}

// ---------------- decoder + mean ----------------
__global__ __launch_bounds__(256) void dec_partial(const float* __restrict__ h,
    const float* __restrict__ W, float* __restrict__ partials, int N)
{
  float acc = 0.f;
  for (int n = blockIdx.x*256 + threadIdx.x; n < N; n += 256*256) {
    const float* hr = h + (size_t)n*D;
    float s = 0.f;
    #pragma unroll
    for (int t = 0; t < 32; t++) {
      float4 hv = ld4(&hr[t*4]); float4 wv = ld4(&W[t*4]);
      s += hv.x*wv.x + hv.y*wv.y + hv.z*wv.z + hv.w*wv.w;
    }
    acc += s;
  }
  #pragma unroll
  for (int off = 1; off < 64; off <<= 1) acc += __shfl_xor(acc, off);
  __shared__ float red[4];
  int lane = threadIdx.x & 63, w = threadIdx.x >> 6;
  if (lane == 0) red[w] = acc;
  __syncthreads();
  if (threadIdx.x == 0) partials[blockIdx.x] = red[0]+red[1]+red[2]+red[3];
}

__global__ __launch_bounds__(256) void dec_final(const float* __restrict__ partials,
    const float* __restrict__ decb, float* __restrict__ out, int N)
{
  float a = partials[threadIdx.x];
  #pragma unroll
  for (int off = 1; off < 64; off <<= 1) a += __shfl_xor(a, off);
  __shared__ float red[4];
  int lane = threadIdx.x & 63, w = threadIdx.x >> 6;
  if (lane == 0) red[w] = a;
  __syncthreads();
  if (threadIdx.x == 0) out[0] = (red[0]+red[1]+red[2]+red[3]) / (float)N + decb[0];
}

// ---------------- launch ----------------
extern "C" void kernel_launch(void* const* d_in, const int* in_sizes, int n_in,
                              void* d_out, int out_size, void* d_ws, size_t ws_size,
                              hipStream_t stream)
{
  const float* nf   = (const float*)d_in[0];
  const int*   src  = (const int*)  d_in[1];
  const int*   dst  = (const int*)  d_in[2];
  const float* encW = (const float*)d_in[3];
  const float* encb = (const float*)d_in[4];
  const float* Wq   = (const float*)d_in[5];
  const float* Wk   = (const float*)d_in[6];
  const float* Wv   = (const float*)d_in[7];
  const float* Wo   = (const float*)d_in[8];
  const float* ln1g = (const float*)d_in[9];
  const float* ln1b = (const float*)d_in[10];
  const float* W1   = (const float*)d_in[11];
  const float* b1   = (const float*)d_in[12];
  const float* W2   = (const float*)d_in[13];
  const float* b2   = (const float*)d_in[14];
  const float* ln2g = (const float*)d_in[15];
  const float* ln2b = (const float*)d_in[16];
  const float* decW = (const float*)d_in[17];
  const float* decb = (const float*)d_in[18];
  float* out = (float*)d_out;

  const int N = in_sizes[0] / 16;
  const int E = in_sizes[1];
  const int NB = (N + 1023) / 1024;

  float* ws   = (float*)d_ws;
  float* h    = ws;                              // [N,128] f32
  float* q    = h  + (size_t)N*128;              // [N,128] f32
  u16*  hb    = (u16*)(q + (size_t)N*128);       // [N,128] bf16
  u16*  kvb   = hb  + (size_t)N*128;             // [N,256] bf16 (k | v)
  u16*  savb  = kvb + (size_t)N*256;             // [N,128] bf16 (attn out)
  int* deg    = (int*)(savb + (size_t)N*128);
  int* offs   = deg + N;
  int* cursor = offs + N + 1;
  int* csr    = cursor + N;                      // holds src-node ids
  int* bsum   = csr + E;
  float* partials = (float*)(bsum + ((NB + 255) & ~255));
  u16* wbuf   = (u16*)(partials + 512);          // bf16 weights
  u16* wqkv   = wbuf;                            // [3][384][128]
  u16* wo_b   = wbuf + 147456;                   // [3][128][128]
  u16* w1_b   = wbuf + 196608;                   // [3][512][128]
  u16* w2_b   = wbuf + 393216;                   // [3][128][512]

  hipMemsetAsync(deg, 0, sizeof(int)*N, stream);
  count_kernel<<<(E+255)/256, 256, 0, stream>>>(dst, deg, E);
  scan_bsum<<<NB, 256, 0, stream>>>(deg, bsum, N);
  scan_bbase<<<1, 64, 0, stream>>>(bsum, NB);
  scan_write<<<NB, 256, 0, stream>>>(deg, bsum, offs, cursor, N);
  fill_kernel<<<(E+255)/256, 256, 0, stream>>>(dst, src, cursor, csr, E);

  convert_weights<<<(589824+255)/256, 256, 0, stream>>>(Wq, Wk, Wv, Wo, W1, W2, wbuf);

  encoder_kernel<<<(N+1)/2, 256, 0, stream>>>(nf, encW, encb, h, hb, N);

  const int gmx = (N + 127)/128;
  for (int l = 0; l < LAYERS; l++) {
    const u16* wqkv_l = wqkv + (size_t)l*384*128;
    const u16* wo_l   = wo_b + (size_t)l*128*128;
    const u16* w1_l   = w1_b + (size_t)l*512*128;
    const u16* w2_l   = w2_b + (size_t)l*128*512;

    gemm_qkv<<<dim3(gmx,3), 256, 0, stream>>>(hb, wqkv_l, q, kvb, N);

    attn_kernel<<<(N+15)/16, 256, 0, stream>>>(q, kvb, offs, csr, savb, N);

    ffn_fused<<<(N+63)/64, 256, 0, stream>>>(
        savb, wo_l, w1_l, w2_l,
        ln1g + l*D, ln1b + l*D, b1 + l*DFF, b2 + l*D, ln2g + l*D, ln2b + l*D,
        h, hb, N);
  }

  dec_partial<<<256, 256, 0, stream>>>(h, decW, partials, N);
  dec_final<<<1, 256, 0, stream>>>(partials, decb, out, N);
}

// Round 7
// 541.891 us; speedup vs baseline: 4.2595x; 1.0268x over previous
//
#include <hip/hip_runtime.h>
#include <math.h>

static constexpr int D   = 128;
static constexpr int DFF = 512;
static constexpr int LAYERS = 3;
static constexpr float CLAMP_V = 5.0f;
static constexpr float LN_EPS = 1e-5f;

typedef unsigned short u16;
typedef unsigned int   u32;
typedef short bf16x8 __attribute__((ext_vector_type(8)));
typedef float f32x4  __attribute__((ext_vector_type(4)));

__device__ inline float4 ld4(const float* p){ return *reinterpret_cast<const float4*>(p); }
__device__ inline u16 f2bf(float f){ u32 u = __float_as_uint(f); return (u16)((u + 0x7fff + ((u>>16)&1)) >> 16); }
__device__ inline float bl(u32 u){ return __uint_as_float(u << 16); }
__device__ inline float bh(u32 u){ return __uint_as_float(u & 0xffff0000u); }

__device__ inline void gload_lds16(const void* g, void* l) {
  __builtin_amdgcn_global_load_lds(
      (const __attribute__((address_space(1))) void*)g,
      (__attribute__((address_space(3))) void*)l, 16, 0, 0);
}

// ---------------- CSR build ----------------
__global__ __launch_bounds__(256) void count_kernel(const int* __restrict__ dst,
                                                    int* __restrict__ deg, int E)
{
  int e = blockIdx.x*256 + threadIdx.x;
  if (e < E) atomicAdd(&deg[dst[e]], 1);
}

__global__ __launch_bounds__(256) void scan_bsum(const int* __restrict__ deg,
                                                 int* __restrict__ bsum, int N)
{
  const int i0 = blockIdx.x*1024 + threadIdx.x*4;
  int s = 0;
  if (i0 + 3 < N) { int4 v = *(const int4*)&deg[i0]; s = v.x+v.y+v.z+v.w; }
  else { for (int t = 0; t < 4; t++) if (i0+t < N) s += deg[i0+t]; }
  #pragma unroll
  for (int off = 1; off < 64; off <<= 1) s += __shfl_xor(s, off);
  __shared__ int ws_[4];
  if ((threadIdx.x & 63) == 0) ws_[threadIdx.x >> 6] = s;
  __syncthreads();
  if (threadIdx.x == 0) bsum[blockIdx.x] = ws_[0]+ws_[1]+ws_[2]+ws_[3];
}

__global__ __launch_bounds__(64) void scan_bbase(int* __restrict__ bsum, int NB)
{
  const int tid = threadIdx.x;
  int base = 0;
  for (int c = 0; c < NB; c += 64) {
    const int idx = c + tid;
    int v = (idx < NB) ? bsum[idx] : 0;
    const int orig = v;
    #pragma unroll
    for (int off = 1; off < 64; off <<= 1) {
      int t = __shfl_up(v, off);
      if (tid >= off) v += t;
    }
    if (idx < NB) bsum[idx] = base + v - orig;
    base += __shfl(v, 63);
  }
}

__global__ __launch_bounds__(256) void scan_write(const int* __restrict__ deg,
    const int* __restrict__ bbase, int* __restrict__ offs, int* __restrict__ cursor, int N)
{
  const int i0 = blockIdx.x*1024 + threadIdx.x*4;
  int v[4] = {0,0,0,0};
  if (i0 + 3 < N) { int4 t = *(const int4*)&deg[i0]; v[0]=t.x; v[1]=t.y; v[2]=t.z; v[3]=t.w; }
  else { for (int t = 0; t < 4; t++) if (i0+t < N) v[t] = deg[i0+t]; }
  const int s = v[0]+v[1]+v[2]+v[3];
  const int lane = threadIdx.x & 63, w = threadIdx.x >> 6;
  int inc = s;
  #pragma unroll
  for (int off = 1; off < 64; off <<= 1) {
    int t = __shfl_up(inc, off);
    if (lane >= off) inc += t;
  }
  __shared__ int wsum[4];
  if (lane == 63) wsum[w] = inc;
  __syncthreads();
  int wb = 0;
  for (int t = 0; t < 4; t++) if (t < w) wb += wsum[t];
  int run = bbase[blockIdx.x] + wb + inc - s;
  #pragma unroll
  for (int t = 0; t < 4; t++) {
    if (i0 + t < N) { offs[i0+t] = run; cursor[i0+t] = run; run += v[t]; }
  }
  if (i0 <= N-1 && N-1 < i0+4) offs[N] = run;
}

__global__ __launch_bounds__(256) void fill_kernel(const int* __restrict__ dst,
    const int* __restrict__ src, int* __restrict__ cursor, int* __restrict__ csr_src, int E)
{
  int e = blockIdx.x*256 + threadIdx.x;
  if (e < E) {
    int p = atomicAdd(&cursor[dst[e]], 1);
    csr_src[p] = src[e];
  }
}

// ---------------- weight conversion to bf16 ----------------
__global__ __launch_bounds__(256) void convert_weights(
    const float* __restrict__ Wq, const float* __restrict__ Wk, const float* __restrict__ Wv,
    const float* __restrict__ Wo, const float* __restrict__ W1, const float* __restrict__ W2,
    u16* __restrict__ out)
{
  const int SQKV = 3*384*128;
  const int SWO  = 3*128*128;
  const int SW1  = 3*512*128;
  const int SW2  = 3*128*512;
  int i = blockIdx.x*256 + threadIdx.x;
  if (i >= SQKV+SWO+SW1+SW2) return;
  float v;
  if (i < SQKV) {
    int l = i / (384*128), rem = i % (384*128);
    int row = rem / 128, col = rem % 128;
    const float* W = (row < 128) ? Wq : ((row < 256) ? Wk : Wv);
    v = W[(size_t)l*128*128 + (size_t)(row & 127)*128 + col];
  } else if (i < SQKV+SWO) {
    v = Wo[i - SQKV];
  } else if (i < SQKV+SWO+SW1) {
    v = W1[i - SQKV - SWO];
  } else {
    v = W2[i - SQKV - SWO - SW1];
  }
  out[i] = f2bf(v);
}

// ---------------- encoder (f32 + bf16 dual write) ----------------
__global__ __launch_bounds__(256) void encoder_kernel(
    const float* __restrict__ nf, const float* __restrict__ W,
    const float* __restrict__ b, float* __restrict__ h, u16* __restrict__ hb, int N)
{
  int n = blockIdx.x*2 + (threadIdx.x >> 7);
  int d = threadIdx.x & 127;
  if (n >= N) return;
  const float* nr = nf + (size_t)n*16;
  const float* wr = W  + (size_t)d*16;
  float s = b[d];
  #pragma unroll
  for (int kk = 0; kk < 16; kk++) s = fmaf(nr[kk], wr[kk], s);
  h[(size_t)n*D + d]  = s;
  hb[(size_t)n*D + d] = f2bf(s);
}

// ---------------- MFMA helpers ----------------
__device__ inline void mfma_step128(const u16* __restrict__ la, const u16* __restrict__ lb,
                                    int lane, int wr, int wc, f32x4 (&acc)[4][4])
{
  #pragma unroll
  for (int k2 = 0; k2 < 2; k2++) {
    bf16x8 af[4], bfr[4];
    const int kq = k2*4 + (lane >> 4);
    #pragma unroll
    for (int mi = 0; mi < 4; mi++) {
      const int r = wr*64 + mi*16 + (lane & 15);
      af[mi] = *(const bf16x8*)&la[r*64 + ((kq ^ (r & 7)) << 3)];
    }
    #pragma unroll
    for (int ni = 0; ni < 4; ni++) {
      const int r = wc*64 + ni*16 + (lane & 15);
      bfr[ni] = *(const bf16x8*)&lb[r*64 + ((kq ^ (r & 7)) << 3)];
    }
    #pragma unroll
    for (int mi = 0; mi < 4; mi++)
      #pragma unroll
      for (int ni = 0; ni < 4; ni++)
        acc[mi][ni] = __builtin_amdgcn_mfma_f32_16x16x32_bf16(af[mi], bfr[ni], acc[mi][ni], 0, 0, 0);
  }
}

__device__ inline void mfma_stage64(const u16* __restrict__ Atile, const u16* __restrict__ Btile,
                                    int lane, int wr, int wc, int kabase, f32x4 (&acc)[2][4])
{
  #pragma unroll
  for (int k2 = 0; k2 < 2; k2++) {
    const int kql = k2*4 + (lane >> 4);
    const int kqa = kabase + kql;
    bf16x8 af[2], bfr[4];
    #pragma unroll
    for (int mi = 0; mi < 2; mi++) {
      const int r = wr*32 + mi*16 + (lane & 15);
      const int slot = ((kqa & 7) ^ (r & 7)) | (kqa & 8);
      af[mi] = *(const bf16x8*)&Atile[r*128 + slot*8];
    }
    #pragma unroll
    for (int ni = 0; ni < 4; ni++) {
      const int r = wc*64 + ni*16 + (lane & 15);
      bfr[ni] = *(const bf16x8*)&Btile[r*64 + ((kql ^ (r & 7)) << 3)];
    }
    #pragma unroll
    for (int mi = 0; mi < 2; mi++)
      #pragma unroll
      for (int ni = 0; ni < 4; ni++)
        acc[mi][ni] = __builtin_amdgcn_mfma_f32_16x16x32_bf16(af[mi], bfr[ni], acc[mi][ni], 0, 0, 0);
  }
}

// ---------------- QKV GEMM: A staged once, 3 weight mats streamed ----------------
__global__ __launch_bounds__(256) void gemm_qkv(
    const u16* __restrict__ A, const u16* __restrict__ B,
    float* __restrict__ qf, u16* __restrict__ kvb, int M)
{
  __shared__ u16 lA[2][128*64];
  __shared__ u16 lW[2][128*64];
  const int m0 = blockIdx.x * 128;
  const int tid = threadIdx.x, lane = tid & 63, wid = tid >> 6;
  const int wr = wid >> 1, wc = wid & 1;
  const int ldrow = lane >> 3;
  const int gran  = (lane & 7) ^ ldrow;

  auto issueA = [&](int ks) {
    const int k0 = ks*64 + gran*8;
    #pragma unroll
    for (int is = 0; is < 4; is++) {
      const int r = wid*32 + is*8;
      int gm = m0 + r + ldrow; if (gm >= M) gm = M - 1;
      gload_lds16(A + (size_t)gm*128 + k0, &lA[ks][r*64]);
    }
  };
  auto issueW = [&](int s) {
    const u16* Bm = B + (size_t)(s >> 1)*128*128;
    const int k0 = (s & 1)*64 + gran*8;
    #pragma unroll
    for (int is = 0; is < 4; is++) {
      const int r = wid*32 + is*8;
      gload_lds16(Bm + (size_t)(r + ldrow)*128 + k0, &lW[s & 1][r*64]);
    }
  };

  issueA(0); issueA(1); issueW(0);

  f32x4 acc[4][4];
  const int rbase = m0 + wr*64 + ((lane >> 4) << 2);
  const int cbase = wc*64 + (lane & 15);

  asm volatile("s_waitcnt vmcnt(0)" ::: "memory");
  __syncthreads();

  #pragma unroll
  for (int s = 0; s < 6; s++) {
    if (s < 5) issueW(s + 1);
    if ((s & 1) == 0) {
      #pragma unroll
      for (int i = 0; i < 4; i++)
        #pragma unroll
        for (int j = 0; j < 4; j++) { acc[i][j][0]=0.f; acc[i][j][1]=0.f; acc[i][j][2]=0.f; acc[i][j][3]=0.f; }
    }
    mfma_step128(lA[s & 1], lW[s & 1], lane, wr, wc, acc);
    if (s & 1) {
      const int mat = s >> 1;
      #pragma unroll
      for (int ni = 0; ni < 4; ni++) {
        const int col = cbase + ni*16;
        #pragma unroll
        for (int mi = 0; mi < 4; mi++) {
          #pragma unroll
          for (int r = 0; r < 4; r++) {
            const int gm = rbase + mi*16 + r;
            if (gm < M) {
              if (mat == 0) qf[(size_t)gm*128 + col] = acc[mi][ni][r];
              else          kvb[(size_t)gm*256 + (mat-1)*128 + col] = f2bf(acc[mi][ni][r]);
            }
          }
        }
      }
    }
    if (s < 5) {
      asm volatile("s_waitcnt vmcnt(0)" ::: "memory");
      __syncthreads();
    }
  }
}

// ---------------- fused per-layer tail, 18-stage software pipeline ----------------
__global__ __launch_bounds__(256) void ffn_fused(
    const u16* __restrict__ savb, const u16* __restrict__ Wo,
    const u16* __restrict__ W1,   const u16* __restrict__ W2,
    const float* __restrict__ ln1g, const float* __restrict__ ln1b,
    const float* __restrict__ b1,   const float* __restrict__ b2,
    const float* __restrict__ ln2g, const float* __restrict__ ln2b,
    float* __restrict__ hf, u16* __restrict__ hb, int M)
{
  __shared__ u16 lB[2][128*64];
  __shared__ u16 h1s[64*128];
  __shared__ u16 fs[64*128];
  __shared__ float lsum[64][2];
  __shared__ float lsq[64][2];

  const int tid  = threadIdx.x;
  const int lane = tid & 63;
  const int wid  = tid >> 6;
  const int wr   = wid >> 1, wc = wid & 1;
  const int m0   = blockIdx.x * 64;

  const int ldrow = lane >> 3;
  const int gran  = (lane & 7) ^ ldrow;

  const int rbase_l = wr*32 + ((lane >> 4) << 2);
  const int cbase   = wc*64 + (lane & 15);

  auto stage_issue = [&](int s) {
    u16* dst = lB[s & 1];
    #pragma unroll
    for (int is = 0; is < 4; is++) {
      const int r = wid*32 + is*8;
      const u16* gp;
      if (s < 2) gp = Wo + (size_t)(r + ldrow)*128 + s*64;
      else {
        const int t = s - 2, c = t >> 2, k = t & 3;
        gp = (k < 2) ? (W1 + (size_t)(c*128 + r + ldrow)*128 + k*64)
                     : (W2 + (size_t)(r + ldrow)*512 + c*128 + (k-2)*64);
      }
      gload_lds16(gp + gran*8, dst + r*64);
    }
  };

  #pragma unroll
  for (int is = 0; is < 4; is++) {
    const int r0 = wid*16 + is*4;
    const int rr = r0 + (lane >> 4);
    int gm = m0 + rr; if (gm >= M) gm = M - 1;
    const int gsrc = ((lane & 7) ^ (rr & 7)) | (lane & 8);
    gload_lds16(savb + (size_t)gm*128 + gsrc*8, &fs[r0*128]);
  }
  stage_issue(0);

  f32x4 acc1[2][4], acc2[2][4], acc3[2][4];
  #pragma unroll
  for (int i = 0; i < 2; i++)
    #pragma unroll
    for (int j = 0; j < 4; j++) {
      acc1[i][j][0]=0.f; acc1[i][j][1]=0.f; acc1[i][j][2]=0.f; acc1[i][j][3]=0.f;
      acc3[i][j][0]=0.f; acc3[i][j][1]=0.f; acc3[i][j][2]=0.f; acc3[i][j][3]=0.f;
    }

  asm volatile("s_waitcnt vmcnt(0)" ::: "memory");
  __syncthreads();

  #pragma unroll
  for (int s = 0; s < 18; s++) {
    if (s < 17) stage_issue(s + 1);

    if (s >= 2 && ((s - 2) & 3) == 0) {
      #pragma unroll
      for (int i = 0; i < 2; i++)
        #pragma unroll
        for (int j = 0; j < 4; j++) { acc2[i][j][0]=0.f; acc2[i][j][1]=0.f; acc2[i][j][2]=0.f; acc2[i][j][3]=0.f; }
    }

    if (s < 2)
      mfma_stage64(fs,  lB[s & 1], lane, wr, wc, (s & 1)*8, acc1);
    else if (((s - 2) & 3) < 2)
      mfma_stage64(h1s, lB[s & 1], lane, wr, wc, (s & 1)*8, acc2);
    else
      mfma_stage64(fs,  lB[s & 1], lane, wr, wc, (s & 1)*8, acc3);

    if (s == 1) {
      #pragma unroll
      for (int mi = 0; mi < 2; mi++) {
        #pragma unroll
        for (int r = 0; r < 4; r++) {
          const int lrow = rbase_l + mi*16 + r;
          int gr = m0 + lrow; if (gr >= M) gr = M - 1;
          float ps = 0.f, pq = 0.f;
          #pragma unroll
          for (int ni = 0; ni < 4; ni++) {
            const int col = cbase + ni*16;
            float x = acc1[mi][ni][r] + hf[(size_t)gr*128 + col];
            acc1[mi][ni][r] = x;
            ps += x; pq += x*x;
          }
          #pragma unroll
          for (int off = 1; off < 16; off <<= 1) { ps += __shfl_xor(ps, off); pq += __shfl_xor(pq, off); }
          if ((lane & 15) == 0) { lsum[lrow][wc] = ps; lsq[lrow][wc] = pq; }
        }
      }
      __syncthreads();
      #pragma unroll
      for (int mi = 0; mi < 2; mi++) {
        #pragma unroll
        for (int r = 0; r < 4; r++) {
          const int lrow = rbase_l + mi*16 + r;
          const float mean = (lsum[lrow][0] + lsum[lrow][1]) * (1.0f/128.0f);
          float var = (lsq[lrow][0] + lsq[lrow][1]) * (1.0f/128.0f) - mean*mean;
          const float rstd = rsqrtf(fmaxf(var, 0.f) + LN_EPS);
          #pragma unroll
          for (int ni = 0; ni < 4; ni++) {
            const int col = cbase + ni*16;
            float o = (acc1[mi][ni][r] - mean) * rstd * ln1g[col] + ln1b[col];
            acc1[mi][ni][r] = o;
            const int g16 = col >> 3;
            const int slot = ((g16 & 7) ^ (lrow & 7)) | (g16 & 8);
            h1s[lrow*128 + slot*8 + (col & 7)] = f2bf(o);
          }
        }
      }
    } else if (s >= 2 && ((s - 2) & 3) == 1) {
      const int c = (s - 2) >> 2;
      #pragma unroll
      for (int mi = 0; mi < 2; mi++) {
        #pragma unroll
        for (int r = 0; r < 4; r++) {
          const int lrow = rbase_l + mi*16 + r;
          #pragma unroll
          for (int ni = 0; ni < 4; ni++) {
            const int col = cbase + ni*16;
            float v = fmaxf(acc2[mi][ni][r] + b1[c*128 + col], 0.f);
            const int g16 = col >> 3;
            const int slot = ((g16 & 7) ^ (lrow & 7)) | (g16 & 8);
            fs[lrow*128 + slot*8 + (col & 7)] = f2bf(v);
          }
        }
      }
    }

    if (s < 17) {
      asm volatile("s_waitcnt vmcnt(0)" ::: "memory");
      __syncthreads();
    }
  }

  #pragma unroll
  for (int mi = 0; mi < 2; mi++) {
    #pragma unroll
    for (int r = 0; r < 4; r++) {
      const int lrow = rbase_l + mi*16 + r;
      float ps = 0.f, pq = 0.f;
      #pragma unroll
      for (int ni = 0; ni < 4; ni++) {
        const int col = cbase + ni*16;
        float x = acc3[mi][ni][r] + b2[col] + acc1[mi][ni][r];
        acc3[mi][ni][r] = x;
        ps += x; pq += x*x;
      }
      #pragma unroll
      for (int off = 1; off < 16; off <<= 1) { ps += __shfl_xor(ps, off); pq += __shfl_xor(pq, off); }
      if ((lane & 15) == 0) { lsum[lrow][wc] = ps; lsq[lrow][wc] = pq; }
    }
  }
  __syncthreads();
  #pragma unroll
  for (int mi = 0; mi < 2; mi++) {
    #pragma unroll
    for (int r = 0; r < 4; r++) {
      const int lrow = rbase_l + mi*16 + r;
      const int grow = m0 + lrow;
      if (grow >= M) continue;
      const float mean = (lsum[lrow][0] + lsum[lrow][1]) * (1.0f/128.0f);
      float var = (lsq[lrow][0] + lsq[lrow][1]) * (1.0f/128.0f) - mean*mean;
      const float rstd = rsqrtf(fmaxf(var, 0.f) + LN_EPS);
      #pragma unroll
      for (int ni = 0; ni < 4; ni++) {
        const int col = cbase + ni*16;
        float o = (acc3[mi][ni][r] - mean) * rstd * ln2g[col] + ln2b[col];
        hf[(size_t)grow*128 + col] = o;
        hb[(size_t)grow*128 + col] = f2bf(o);
      }
    }
  }
}

// ---------------- attention: single-pass, 16-edge full batch (32 loads in flight) ----------------
__global__ __launch_bounds__(256) void attn_kernel(
    const float* __restrict__ q, const u16* __restrict__ kv,
    const int* __restrict__ offs, const int* __restrict__ csr_src,
    u16* __restrict__ outb, int N)
{
  const int tid = threadIdx.x;
  const int j   = tid & 15;
  const int n   = blockIdx.x*16 + (tid >> 4);
  if (n >= N) return;

  float qreg[8];
  *(float4*)&qreg[0] = ld4(&q[(size_t)n*128 + j*8]);
  *(float4*)&qreg[4] = ld4(&q[(size_t)n*128 + j*8 + 4]);

  const int start = offs[n];
  const int deg   = offs[n+1] - start;

  float s = 0.f;
  float acc[8] = {0,0,0,0,0,0,0,0};
  const int gb = tid & 48;

  for (int base = 0; base < deg; base += 16) {
    const int myidx = base + j;
    const int sn_mine = (myidx < deg) ? csr_src[start + myidx] : 0;
    const int cnt = (deg - base < 16) ? (deg - base) : 16;

    uint4 K4[16], V4[16];
    #pragma unroll
    for (int u = 0; u < 16; u++) {
      const int sel = (u < cnt) ? u : 0;
      const int sn = __shfl(sn_mine, gb + sel);
      const u16* row = kv + (size_t)sn*256 + j*8;
      K4[u] = *(const uint4*)row;
      V4[u] = *(const uint4*)(row + 128);
    }
    #pragma unroll
    for (int u = 0; u < 16; u++) {
      if (u < cnt) {
        float d = bl(K4[u].x)*qreg[0] + bh(K4[u].x)*qreg[1]
                + bl(K4[u].y)*qreg[2] + bh(K4[u].y)*qreg[3]
                + bl(K4[u].z)*qreg[4] + bh(K4[u].z)*qreg[5]
                + bl(K4[u].w)*qreg[6] + bh(K4[u].w)*qreg[7];
        d += __shfl_xor(d, 1);
        float uu = fminf(fmaxf(d * 0.25f, -CLAMP_V), CLAMP_V);
        float e = __expf(uu - CLAMP_V);
        s += e;
        acc[0] = fmaf(e, bl(V4[u].x), acc[0]);
        acc[1] = fmaf(e, bh(V4[u].x), acc[1]);
        acc[2] = fmaf(e, bl(V4[u].y), acc[2]);
        acc[3] = fmaf(e, bh(V4[u].y), acc[3]);
        acc[4] = fmaf(e, bl(V4[u].z), acc[4]);
        acc[5] = fmaf(e, bh(V4[u].z), acc[5]);
        acc[6] = fmaf(e, bl(V4[u].w), acc[6]);
        acc[7] = fmaf(e, bh(V4[u].w), acc[7]);
      }
    }
  }

  const float rs = (deg > 0) ? (1.0f / s) : 0.f;
  u16 o[8];
  #pragma unroll
  for (int t = 0; t < 8; t++) o[t] = f2bf(acc[t] * rs);
  *(uint4*)&outb[(size_t)n*128 + j*8] = *(const uint4*)o;
}

// ---------------- decoder + mean ----------------
__global__ __launch_bounds__(256) void dec_partial(const float* __restrict__ h,
    const float* __restrict__ W, float* __restrict__ partials, int N)
{
  float acc = 0.f;
  for (int n = blockIdx.x*256 + threadIdx.x; n < N; n += 256*256) {
    const float* hr = h + (size_t)n*D;
    float s = 0.f;
    #pragma unroll
    for (int t = 0; t < 32; t++) {
      float4 hv = ld4(&hr[t*4]); float4 wv = ld4(&W[t*4]);
      s += hv.x*wv.x + hv.y*wv.y + hv.z*wv.z + hv.w*wv.w;
    }
    acc += s;
  }
  #pragma unroll
  for (int off = 1; off < 64; off <<= 1) acc += __shfl_xor(acc, off);
  __shared__ float red[4];
  int lane = threadIdx.x & 63, w = threadIdx.x >> 6;
  if (lane == 0) red[w] = acc;
  __syncthreads();
  if (threadIdx.x == 0) partials[blockIdx.x] = red[0]+red[1]+red[2]+red[3];
}

__global__ __launch_bounds__(256) void dec_final(const float* __restrict__ partials,
    const float* __restrict__ decb, float* __restrict__ out, int N)
{
  float a = partials[threadIdx.x];
  #pragma unroll
  for (int off = 1; off < 64; off <<= 1) a += __shfl_xor(a, off);
  __shared__ float red[4];
  int lane = threadIdx.x & 63, w = threadIdx.x >> 6;
  if (lane == 0) red[w] = a;
  __syncthreads();
  if (threadIdx.x == 0) out[0] = (red[0]+red[1]+red[2]+red[3]) / (float)N + decb[0];
}

// ---------------- launch ----------------
extern "C" void kernel_launch(void* const* d_in, const int* in_sizes, int n_in,
                              void* d_out, int out_size, void* d_ws, size_t ws_size,
                              hipStream_t stream)
{
  const float* nf   = (const float*)d_in[0];
  const int*   src  = (const int*)  d_in[1];
  const int*   dst  = (const int*)  d_in[2];
  const float* encW = (const float*)d_in[3];
  const float* encb = (const float*)d_in[4];
  const float* Wq   = (const float*)d_in[5];
  const float* Wk   = (const float*)d_in[6];
  const float* Wv   = (const float*)d_in[7];
  const float* Wo   = (const float*)d_in[8];
  const float* ln1g = (const float*)d_in[9];
  const float* ln1b = (const float*)d_in[10];
  const float* W1   = (const float*)d_in[11];
  const float* b1   = (const float*)d_in[12];
  const float* W2   = (const float*)d_in[13];
  const float* b2   = (const float*)d_in[14];
  const float* ln2g = (const float*)d_in[15];
  const float* ln2b = (const float*)d_in[16];
  const float* decW = (const float*)d_in[17];
  const float* decb = (const float*)d_in[18];
  float* out = (float*)d_out;

  const int N = in_sizes[0] / 16;
  const int E = in_sizes[1];
  const int NB = (N + 1023) / 1024;

  float* ws   = (float*)d_ws;
  float* h    = ws;                              // [N,128] f32
  float* q    = h  + (size_t)N*128;              // [N,128] f32
  u16*  hb    = (u16*)(q + (size_t)N*128);       // [N,128] bf16
  u16*  kvb   = hb  + (size_t)N*128;             // [N,256] bf16 (k | v)
  u16*  savb  = kvb + (size_t)N*256;             // [N,128] bf16 (attn out)
  int* deg    = (int*)(savb + (size_t)N*128);
  int* offs   = deg + N;
  int* cursor = offs + N + 1;
  int* csr    = cursor + N;                      // holds src-node ids
  int* bsum   = csr + E;
  float* partials = (float*)(bsum + ((NB + 255) & ~255));
  u16* wbuf   = (u16*)(partials + 512);          // bf16 weights
  u16* wqkv   = wbuf;                            // [3][384][128]
  u16* wo_b   = wbuf + 147456;                   // [3][128][128]
  u16* w1_b   = wbuf + 196608;                   // [3][512][128]
  u16* w2_b   = wbuf + 393216;                   // [3][128][512]

  hipMemsetAsync(deg, 0, sizeof(int)*N, stream);
  count_kernel<<<(E+255)/256, 256, 0, stream>>>(dst, deg, E);
  scan_bsum<<<NB, 256, 0, stream>>>(deg, bsum, N);
  scan_bbase<<<1, 64, 0, stream>>>(bsum, NB);
  scan_write<<<NB, 256, 0, stream>>>(deg, bsum, offs, cursor, N);
  fill_kernel<<<(E+255)/256, 256, 0, stream>>>(dst, src, cursor, csr, E);

  convert_weights<<<(589824+255)/256, 256, 0, stream>>>(Wq, Wk, Wv, Wo, W1, W2, wbuf);

  encoder_kernel<<<(N+1)/2, 256, 0, stream>>>(nf, encW, encb, h, hb, N);

  const int gmx = (N + 127)/128;
  for (int l = 0; l < LAYERS; l++) {
    const u16* wqkv_l = wqkv + (size_t)l*384*128;
    const u16* wo_l   = wo_b + (size_t)l*128*128;
    const u16* w1_l   = w1_b + (size_t)l*512*128;
    const u16* w2_l   = w2_b + (size_t)l*128*512;

    gemm_qkv<<<gmx, 256, 0, stream>>>(hb, wqkv_l, q, kvb, N);

    attn_kernel<<<(N+15)/16, 256, 0, stream>>>(q, kvb, offs, csr, savb, N);

    ffn_fused<<<(N+63)/64, 256, 0, stream>>>(
        savb, wo_l, w1_l, w2_l,
        ln1g + l*D, ln1b + l*D, b1 + l*DFF, b2 + l*D, ln2g + l*D, ln2b + l*D,
        h, hb, N);
  }

  dec_partial<<<256, 256, 0, stream>>>(h, decW, partials, N);
  dec_final<<<1, 256, 0, stream>>>(partials, decb, out, N);
}